// Round 7
// baseline (492.366 us; speedup 1.0000x reference)
//
#include <hip/hip_runtime.h>
#include <hip/hip_bf16.h>

// Problem constants
constexpr int Bn = 4, Sn = 2048, Dn = 1024, Hn = 16, DKn = 64;
constexpr int Mrows = Bn * Sn;  // 8192
constexpr int NQB = Sn / 64;    // 32 q-chunks of 64 rows

typedef __attribute__((ext_vector_type(8))) short short8;
typedef __attribute__((ext_vector_type(4))) float f32x4;
typedef __attribute__((ext_vector_type(4))) unsigned int u32x4;

#define DEV __device__ __forceinline__

// fp32 -> bf16 RNE, scalar (epilogue scatter only)
DEV unsigned short f2bf(float f) {
    unsigned u = __builtin_bit_cast(unsigned, f);
    u += 0x7FFFu + ((u >> 16) & 1u);
    return (unsigned short)(u >> 16);
}
// fp32 pair -> packed bf16x2 via v_cvt_pk_bf16_f32 (hardware RNE)
DEV unsigned pk2(float a, float b) {
    __hip_bfloat162 h = __float22bfloat162_rn(float2{a, b});
    unsigned u;
    __builtin_memcpy(&u, &h, 4);
    return u;
}
// 2^x via v_exp_f32
DEV float exp2a(float x) {
    float r;
    asm("v_exp_f32 %0, %1" : "=v"(r) : "v"(x));
    return r;
}

// ---------------------------------------------------------------------------
// GEMM: C[m,n] = sum_k A[m,k] * W[n,k]   (y = x @ W^T), M=8192, N=K=1024.
// 128x128 tile, BK=32, 256 threads (4 waves, 2x2 wave grid, 64x64 per wave).
// Reg-prefetch of next K-step during compute.
// ---------------------------------------------------------------------------
template <bool ABF16, bool OUTF32>
__global__ __launch_bounds__(256) void gemm_nt(const void* __restrict__ Ap,
                                               const float* __restrict__ Bw,
                                               void* __restrict__ Out) {
    __shared__ alignas(16) unsigned short As[128 * 40];
    __shared__ alignas(16) unsigned short Bs[128 * 40];

    const int tid = threadIdx.x;
    const int n0 = blockIdx.x * 128;
    const int m0 = blockIdx.y * 128;
    const int lane = tid & 63;
    const int w = tid >> 6;
    const int wm = (w >> 1) * 64, wn = (w & 1) * 64;
    const int g = lane >> 4, q15 = lane & 15;

    f32x4 acc[4][4] = {};

    const int srow = tid >> 1, shalf = tid & 1;

    const float* Af = (const float*)Ap;
    const unsigned short* Ab = (const unsigned short*)Ap;

    float4 fa0, fa1, fa2, fa3, fb0, fb1, fb2, fb3;
    u32x4 ua0, ua1;

    auto loadA = [&](int kk) {
        if constexpr (ABF16) {
            const u32x4* s =
                (const u32x4*)(Ab + (size_t)(m0 + srow) * Dn + kk + shalf * 16);
            ua0 = s[0];
            ua1 = s[1];
        } else {
            const float4* s =
                (const float4*)(Af + (size_t)(m0 + srow) * Dn + kk + shalf * 16);
            fa0 = s[0]; fa1 = s[1]; fa2 = s[2]; fa3 = s[3];
        }
    };
    auto loadB = [&](int kk) {
        const float4* s =
            (const float4*)(Bw + (size_t)(n0 + srow) * Dn + kk + shalf * 16);
        fb0 = s[0]; fb1 = s[1]; fb2 = s[2]; fb3 = s[3];
    };
    auto store = [&]() {
        u32x4* da = (u32x4*)(&As[srow * 40 + shalf * 16]);
        if constexpr (ABF16) {
            da[0] = ua0;
            da[1] = ua1;
        } else {
            u32x4 p0 = {pk2(fa0.x, fa0.y), pk2(fa0.z, fa0.w), pk2(fa1.x, fa1.y),
                        pk2(fa1.z, fa1.w)};
            u32x4 p1 = {pk2(fa2.x, fa2.y), pk2(fa2.z, fa2.w), pk2(fa3.x, fa3.y),
                        pk2(fa3.z, fa3.w)};
            da[0] = p0;
            da[1] = p1;
        }
        u32x4* db = (u32x4*)(&Bs[srow * 40 + shalf * 16]);
        u32x4 q0 = {pk2(fb0.x, fb0.y), pk2(fb0.z, fb0.w), pk2(fb1.x, fb1.y),
                    pk2(fb1.z, fb1.w)};
        u32x4 q1 = {pk2(fb2.x, fb2.y), pk2(fb2.z, fb2.w), pk2(fb3.x, fb3.y),
                    pk2(fb3.z, fb3.w)};
        db[0] = q0;
        db[1] = q1;
    };

    loadA(0);
    loadB(0);
    for (int kk = 0; kk < Dn; kk += 32) {
        store();
        __syncthreads();
        if (kk + 32 < Dn) {
            loadA(kk + 32);
            loadB(kk + 32);
        }

        short8 af[4], bf[4];
#pragma unroll
        for (int mf = 0; mf < 4; ++mf)
            af[mf] = __builtin_bit_cast(
                short8, *(const u32x4*)(&As[(wm + mf * 16 + q15) * 40 + g * 8]));
#pragma unroll
        for (int nf = 0; nf < 4; ++nf)
            bf[nf] = __builtin_bit_cast(
                short8, *(const u32x4*)(&Bs[(wn + nf * 16 + q15) * 40 + g * 8]));
#pragma unroll
        for (int mf = 0; mf < 4; ++mf)
#pragma unroll
            for (int nf = 0; nf < 4; ++nf)
                acc[mf][nf] = __builtin_amdgcn_mfma_f32_16x16x32_bf16(
                    af[mf], bf[nf], acc[mf][nf], 0, 0, 0);
        __syncthreads();
    }

#pragma unroll
    for (int mf = 0; mf < 4; ++mf)
#pragma unroll
        for (int nf = 0; nf < 4; ++nf)
#pragma unroll
            for (int r = 0; r < 4; ++r) {
                int m = m0 + wm + mf * 16 + 4 * g + r;
                int n = n0 + wn + nf * 16 + q15;
                float val = acc[mf][nf][r];
                if (OUTF32) {
                    ((float*)Out)[(size_t)m * Dn + n] = val;
                } else {
                    int b = m >> 11, s = m & (Sn - 1);
                    int h = n >> 6, dk = n & 63;
                    ((unsigned short*)Out)[(((size_t)(b * Hn + h) * Sn + s) << 6) +
                                           dk] = f2bf(val);
                }
            }
}

// ---------------------------------------------------------------------------
// Causal flash attention, DUAL-CHUNK blocks: block p owns q-chunks
// A = 31-p and B = p, processed in the SAME KV loop so both consume each
// staged KV tile (B active while j <= p). Compute balanced: (32-p)+(p+1)=33
// chunk-iterations per block; KV staged (32-p) times (was 33).
// 256 threads = 4 waves; lane q15 owns one q row per chunk.
// LDS: Kt [64kv][64dk] swizzled; Vt [64dk][64kv] transposed+swizzled.
// QK^T and PV both operand-swapped; softmax in log2 domain with T13
// defer-max; KV tile reg-prefetched (T14).
// ---------------------------------------------------------------------------
__global__ __launch_bounds__(256, 4) void attn_fwd(
    const unsigned short* __restrict__ Qb, const unsigned short* __restrict__ Kb,
    const unsigned short* __restrict__ Vb, unsigned short* __restrict__ Xb) {
    __shared__ alignas(16) unsigned short Kt[64 * 64];
    __shared__ alignas(16) unsigned short Vt[64 * 64];

    constexpr float SCL = 0.18033688f;  // 0.125 * log2(e)

    const int tid = threadIdx.x;
    const int pair = blockIdx.x;  // 0..15
    const int bh = blockIdx.y;
    const int b = bh >> 4, h = bh & 15;
    const int lane = tid & 63, w = tid >> 6;
    const int g = lane >> 4, q15 = lane & 15;

    const unsigned short* Qh = Qb + (size_t)bh * Sn * DKn;
    const unsigned short* Kh = Kb + (size_t)bh * Sn * DKn;
    const unsigned short* Vh = Vb + (size_t)bh * Sn * DKn;

    const int st_row = tid >> 2, st_seg = tid & 3;  // K staging
    const int sv_kv = tid & 63, sv_g = tid >> 6;    // V staging
    const int sel = sv_kv & 1;
    const unsigned kvp = (unsigned)((sv_kv & ~1) * 2);  // byte col base in Vt

    const int jmaxA = NQB - 1 - pair;  // chunk A (long)
    const int jmaxB = pair;            // chunk B (short)
    const int qgA = jmaxA * 64 + w * 16 + q15;
    const int qgB = jmaxB * 64 + w * 16 + q15;

    short8 qfA[2], qfB[2];
#pragma unroll
    for (int ks = 0; ks < 2; ++ks) {
        qfA[ks] = __builtin_bit_cast(
            short8, *(const u32x4*)(Qh + (size_t)qgA * DKn + ks * 32 + g * 8));
        qfB[ks] = __builtin_bit_cast(
            short8, *(const u32x4*)(Qh + (size_t)qgB * DKn + ks * 32 + g * 8));
    }

    f32x4 xaccA[4] = {}, xaccB[4] = {};
    float mA = -1e30f, lA = 0.f, mB = -1e30f, lB = 0.f;

    u32x4 kr0, kr1, vr0, vr1;  // prefetch registers
    auto load_kv = [&](int j) {
        kr0 = *(const u32x4*)(Kh + (size_t)(j * 64 + st_row) * DKn + st_seg * 8);
        kr1 = *(const u32x4*)(Kh + (size_t)(j * 64 + st_row) * DKn +
                              (st_seg + 4) * 8);
        vr0 = *(const u32x4*)(Vh + (size_t)(j * 64 + sv_kv) * DKn + sv_g * 8);
        vr1 = *(const u32x4*)(Vh + (size_t)(j * 64 + sv_kv) * DKn + sv_g * 8 + 32);
    };

    // one chunk-iteration against the currently staged KV tile
    auto compute_chunk = [&](const short8 (&qf)[2], f32x4 (&xacc)[4],
                             float& m_run, float& l_run, int qg, int j,
                             bool diag) {
        // QK^T (swapped): sacc rows = kv, cols = q
        f32x4 sacc[4] = {};
#pragma unroll
        for (int mf = 0; mf < 4; ++mf) {
            int row = mf * 16 + q15;
#pragma unroll
            for (int ks = 0; ks < 2; ++ks) {
                unsigned byteoff = ((unsigned)(row * 128 + ks * 64 + g * 16)) ^
                                   ((unsigned)(row & 7) << 4);
                short8 kf =
                    __builtin_bit_cast(short8, *(const u32x4*)((char*)Kt + byteoff));
                sacc[mf] = __builtin_amdgcn_mfma_f32_16x16x32_bf16(kf, qf[ks],
                                                                   sacc[mf], 0, 0, 0);
            }
        }

        // mask + online softmax (log2 domain), lane owns q row qg
        float p[4][4];
        float pmax = -1e30f;
#pragma unroll
        for (int mf = 0; mf < 4; ++mf)
#pragma unroll
            for (int r = 0; r < 4; ++r) {
                float sv = sacc[mf][r] * SCL;
                if (diag) {
                    int kvg = j * 64 + mf * 16 + 4 * g + r;
                    if (kvg > qg) sv = -1e30f;
                }
                p[mf][r] = sv;
                pmax = fmaxf(pmax, sv);
            }
        pmax = fmaxf(pmax, __shfl_xor(pmax, 16));
        pmax = fmaxf(pmax, __shfl_xor(pmax, 32));
        if (__any(pmax > m_run + 8.f)) {  // T13 defer-max
            float mnew = fmaxf(m_run, pmax);
            float corr = exp2a(m_run - mnew);
            l_run *= corr;
#pragma unroll
            for (int mf = 0; mf < 4; ++mf)
#pragma unroll
                for (int r = 0; r < 4; ++r) xacc[mf][r] *= corr;
            m_run = mnew;
        }
        float lsum = 0.f;
#pragma unroll
        for (int mf = 0; mf < 4; ++mf)
#pragma unroll
            for (int r = 0; r < 4; ++r) {
                float e = exp2a(p[mf][r] - m_run);
                p[mf][r] = e;
                lsum += e;
            }
        lsum += __shfl_xor(lsum, 16);
        lsum += __shfl_xor(lsum, 32);
        l_run += lsum;

        // pack P pairs; PV as O^T = mfma(A=Vt, B=P^T)
        unsigned pkk[4][2];
#pragma unroll
        for (int mf = 0; mf < 4; ++mf) {
            pkk[mf][0] = pk2(p[mf][0], p[mf][1]);
            pkk[mf][1] = pk2(p[mf][2], p[mf][3]);
        }
#pragma unroll
        for (int ks = 0; ks < 2; ++ks) {
            unsigned bw[4];
#pragma unroll
            for (int w2 = 0; w2 < 4; ++w2) {
                // dest (g,q15) needs P[q15][kv=ks*32+g*8+2*w2,+1] =
                // pkk[2*ks+(g>>1)][w2&1] of lane g_src=2*(g&1)+(w2>>1).
                // Shuffle BOTH mf candidates (lane-invariant indices), select
                // on dest side (shfl evaluates on the SOURCE lane).
                int srcl = (2 * (g & 1) + (w2 >> 1)) * 16 + q15;
                unsigned v0 = (unsigned)__shfl((int)pkk[2 * ks][w2 & 1], srcl);
                unsigned v1 = (unsigned)__shfl((int)pkk[2 * ks + 1][w2 & 1], srcl);
                bw[w2] = (g & 2) ? v1 : v0;
            }
            u32x4 tmp = {bw[0], bw[1], bw[2], bw[3]};
            short8 pb = __builtin_bit_cast(short8, tmp);
#pragma unroll
            for (int mf = 0; mf < 4; ++mf) {
                int row = mf * 16 + q15;
                unsigned byteoff = ((unsigned)(row * 128 + ks * 64 + g * 16)) ^
                                   ((unsigned)(row & 7) << 4);
                short8 vf =
                    __builtin_bit_cast(short8, *(const u32x4*)((char*)Vt + byteoff));
                xacc[mf] = __builtin_amdgcn_mfma_f32_16x16x32_bf16(vf, pb,
                                                                   xacc[mf], 0, 0, 0);
            }
        }
    };

    load_kv(0);
    for (int j = 0; j <= jmaxA; ++j) {
        // ---- write staged KV regs to LDS ----
        {
            unsigned b0 = ((unsigned)(st_row * 128 + st_seg * 16)) ^
                          ((unsigned)(st_row & 7) << 4);
            unsigned b1 = ((unsigned)(st_row * 128 + (st_seg + 4) * 16)) ^
                          ((unsigned)(st_row & 7) << 4);
            *(u32x4*)((char*)Kt + b0) = kr0;
            *(u32x4*)((char*)Kt + b1) = kr1;
        }
#pragma unroll
        for (int r2 = 0; r2 < 2; ++r2) {
            u32x4 vvec = r2 ? vr1 : vr0;
            int dk0 = sv_g * 8 + r2 * 32;
#pragma unroll
            for (int i = 0; i < 4; ++i) {
                unsigned mine = vvec[i];
                unsigned theirs = (unsigned)__shfl_xor((int)mine, 1);
                int dk_abs = dk0 + 2 * i + sel;
                unsigned out = sel ? ((theirs >> 16) | (mine & 0xffff0000u))
                                   : ((mine & 0xffffu) | (theirs << 16));
                unsigned byteoff = ((unsigned)(dk_abs * 128) + kvp) ^
                                   ((unsigned)(dk_abs & 7) << 4);
                *(unsigned*)((char*)Vt + byteoff) = out;
            }
        }
        __syncthreads();

        // T14: next tile's loads in flight under the compute
        if (j < jmaxA) load_kv(j + 1);

        compute_chunk(qfA, xaccA, mA, lA, qgA, j, j == jmaxA);
        if (j <= jmaxB) compute_chunk(qfB, xaccB, mB, lB, qgB, j, j == jmaxB);

        __syncthreads();
    }

    // ---- epilogue: lane owns q=q15 row of each chunk; 4x 8B stores ----
    {
        float inv = 1.0f / lA;
        size_t rowbase =
            (size_t)(b * Sn + jmaxA * 64 + w * 16 + q15) * Dn + h * 64;
#pragma unroll
        for (int mf = 0; mf < 4; ++mf) {
            unsigned w0 = pk2(xaccA[mf][0] * inv, xaccA[mf][1] * inv);
            unsigned w1 = pk2(xaccA[mf][2] * inv, xaccA[mf][3] * inv);
            uint2 val = {w0, w1};
            *(uint2*)(Xb + rowbase + mf * 16 + 4 * g) = val;
        }
    }
    {
        float inv = 1.0f / lB;
        size_t rowbase =
            (size_t)(b * Sn + jmaxB * 64 + w * 16 + q15) * Dn + h * 64;
#pragma unroll
        for (int mf = 0; mf < 4; ++mf) {
            unsigned w0 = pk2(xaccB[mf][0] * inv, xaccB[mf][1] * inv);
            unsigned w1 = pk2(xaccB[mf][2] * inv, xaccB[mf][3] * inv);
            uint2 val = {w0, w1};
            *(uint2*)(Xb + rowbase + mf * 16 + 4 * g) = val;
        }
    }
}

// ---------------------------------------------------------------------------
// Launch. ws layout (bf16): Qb | Kb | Vb | Xb, each 8192*1024 elems = 16 MiB.
// Q/K/V head-major [B,H,S,DK]; Xb row-major [B*S, D].
// ---------------------------------------------------------------------------
extern "C" void kernel_launch(void* const* d_in, const int* in_sizes, int n_in,
                              void* d_out, int out_size, void* d_ws, size_t ws_size,
                              hipStream_t stream) {
    (void)in_sizes; (void)n_in; (void)out_size; (void)ws_size;
    const float* q = (const float*)d_in[0];
    const float* k = (const float*)d_in[1];
    const float* v = (const float*)d_in[2];
    // d_in[3] = mask (causal tril; implemented analytically)
    const float* Wq = (const float*)d_in[4];
    const float* Wk = (const float*)d_in[5];
    const float* Wv = (const float*)d_in[6];
    const float* Wo = (const float*)d_in[7];

    unsigned short* Qb = (unsigned short*)d_ws;
    unsigned short* Kb = Qb + (size_t)Mrows * Dn;
    unsigned short* Vb = Kb + (size_t)Mrows * Dn;
    unsigned short* Xb = Vb + (size_t)Mrows * Dn;

    dim3 blk(256);
    dim3 ggrid(Dn / 128, Mrows / 128);

    gemm_nt<false, false><<<ggrid, blk, 0, stream>>>((const void*)q, Wq, (void*)Qb);
    gemm_nt<false, false><<<ggrid, blk, 0, stream>>>((const void*)k, Wk, (void*)Kb);
    gemm_nt<false, false><<<ggrid, blk, 0, stream>>>((const void*)v, Wv, (void*)Vb);

    attn_fwd<<<dim3(NQB / 2, Bn * Hn), blk, 0, stream>>>(Qb, Kb, Vb, Xb);

    gemm_nt<true, true><<<ggrid, blk, 0, stream>>>((const void*)Xb, Wo, d_out);
}

// Round 9
// 284.984 us; speedup vs baseline: 1.7277x; 1.7277x over previous
//
#include <hip/hip_runtime.h>
#include <hip/hip_bf16.h>

// Problem constants
constexpr int Bn = 4, Sn = 2048, Dn = 1024, Hn = 16, DKn = 64;
constexpr int Mrows = Bn * Sn;  // 8192
constexpr int NQB = Sn / 64;    // 32 q-chunks of 64 rows

typedef __attribute__((ext_vector_type(8))) short short8;
typedef __attribute__((ext_vector_type(4))) float f32x4;
typedef __attribute__((ext_vector_type(4))) unsigned int u32x4;

#define DEV __device__ __forceinline__

// fp32 -> bf16 RNE, scalar (epilogue scatter only)
DEV unsigned short f2bf(float f) {
    unsigned u = __builtin_bit_cast(unsigned, f);
    u += 0x7FFFu + ((u >> 16) & 1u);
    return (unsigned short)(u >> 16);
}
// fp32 pair -> packed bf16x2 via v_cvt_pk_bf16_f32 (hardware RNE)
DEV unsigned pk2(float a, float b) {
    __hip_bfloat162 h = __float22bfloat162_rn(float2{a, b});
    unsigned u;
    __builtin_memcpy(&u, &h, 4);
    return u;
}
// 2^x via v_exp_f32
DEV float exp2a(float x) {
    float r;
    asm("v_exp_f32 %0, %1" : "=v"(r) : "v"(x));
    return r;
}

// ---------------------------------------------------------------------------
// Weights fp32 -> bf16, one matrix per blockIdx.y. 8 elems/thread.
// ---------------------------------------------------------------------------
__global__ __launch_bounds__(256) void cvt_w(const float* __restrict__ W0,
                                             const float* __restrict__ W1,
                                             const float* __restrict__ W2,
                                             const float* __restrict__ W3,
                                             unsigned short* __restrict__ Out) {
    const float* src = blockIdx.y == 0 ? W0
                     : blockIdx.y == 1 ? W1
                     : blockIdx.y == 2 ? W2 : W3;
    size_t off = ((size_t)blockIdx.x * 256 + threadIdx.x) * 8;
    const float4* s = (const float4*)(src + off);
    float4 a = s[0], b = s[1];
    u32x4 p = {pk2(a.x, a.y), pk2(a.z, a.w), pk2(b.x, b.y), pk2(b.z, b.w)};
    *(u32x4*)(Out + (size_t)blockIdx.y * (Dn * Dn) + off) = p;
}

// ---------------------------------------------------------------------------
// GEMM: C[m,n] = sum_k A[m,k] * W[n,k]   (y = x @ W^T), M=8192, N=K=1024.
// 128x128 tile, BK=32, 256 threads (4 waves, 2x2 wave grid, 64x64 per wave).
// Reg-prefetch of next K-step during compute. A/B optionally bf16.
// ---------------------------------------------------------------------------
template <bool ABF16, bool BBF16, bool OUTF32>
__global__ __launch_bounds__(256) void gemm_nt(const void* __restrict__ Ap,
                                               const void* __restrict__ Bw,
                                               void* __restrict__ Out) {
    __shared__ alignas(16) unsigned short As[128 * 40];
    __shared__ alignas(16) unsigned short Bs[128 * 40];

    const int tid = threadIdx.x;
    const int n0 = blockIdx.x * 128;
    const int m0 = blockIdx.y * 128;
    const int lane = tid & 63;
    const int w = tid >> 6;
    const int wm = (w >> 1) * 64, wn = (w & 1) * 64;
    const int g = lane >> 4, q15 = lane & 15;

    f32x4 acc[4][4] = {};

    const int srow = tid >> 1, shalf = tid & 1;

    const float* Af = (const float*)Ap;
    const unsigned short* Ab = (const unsigned short*)Ap;
    const float* Bf = (const float*)Bw;
    const unsigned short* Bb = (const unsigned short*)Bw;

    float4 fa0, fa1, fa2, fa3, fb0, fb1, fb2, fb3;
    u32x4 ua0, ua1, ub0, ub1;

    auto loadA = [&](int kk) {
        if constexpr (ABF16) {
            const u32x4* s =
                (const u32x4*)(Ab + (size_t)(m0 + srow) * Dn + kk + shalf * 16);
            ua0 = s[0];
            ua1 = s[1];
        } else {
            const float4* s =
                (const float4*)(Af + (size_t)(m0 + srow) * Dn + kk + shalf * 16);
            fa0 = s[0]; fa1 = s[1]; fa2 = s[2]; fa3 = s[3];
        }
    };
    auto loadB = [&](int kk) {
        if constexpr (BBF16) {
            const u32x4* s =
                (const u32x4*)(Bb + (size_t)(n0 + srow) * Dn + kk + shalf * 16);
            ub0 = s[0];
            ub1 = s[1];
        } else {
            const float4* s =
                (const float4*)(Bf + (size_t)(n0 + srow) * Dn + kk + shalf * 16);
            fb0 = s[0]; fb1 = s[1]; fb2 = s[2]; fb3 = s[3];
        }
    };
    auto store = [&]() {
        u32x4* da = (u32x4*)(&As[srow * 40 + shalf * 16]);
        if constexpr (ABF16) {
            da[0] = ua0;
            da[1] = ua1;
        } else {
            u32x4 p0 = {pk2(fa0.x, fa0.y), pk2(fa0.z, fa0.w), pk2(fa1.x, fa1.y),
                        pk2(fa1.z, fa1.w)};
            u32x4 p1 = {pk2(fa2.x, fa2.y), pk2(fa2.z, fa2.w), pk2(fa3.x, fa3.y),
                        pk2(fa3.z, fa3.w)};
            da[0] = p0;
            da[1] = p1;
        }
        u32x4* db = (u32x4*)(&Bs[srow * 40 + shalf * 16]);
        if constexpr (BBF16) {
            db[0] = ub0;
            db[1] = ub1;
        } else {
            u32x4 q0 = {pk2(fb0.x, fb0.y), pk2(fb0.z, fb0.w), pk2(fb1.x, fb1.y),
                        pk2(fb1.z, fb1.w)};
            u32x4 q1 = {pk2(fb2.x, fb2.y), pk2(fb2.z, fb2.w), pk2(fb3.x, fb3.y),
                        pk2(fb3.z, fb3.w)};
            db[0] = q0;
            db[1] = q1;
        }
    };

    loadA(0);
    loadB(0);
    for (int kk = 0; kk < Dn; kk += 32) {
        store();
        __syncthreads();
        if (kk + 32 < Dn) {
            loadA(kk + 32);
            loadB(kk + 32);
        }

        short8 af[4], bf[4];
#pragma unroll
        for (int mf = 0; mf < 4; ++mf)
            af[mf] = __builtin_bit_cast(
                short8, *(const u32x4*)(&As[(wm + mf * 16 + q15) * 40 + g * 8]));
#pragma unroll
        for (int nf = 0; nf < 4; ++nf)
            bf[nf] = __builtin_bit_cast(
                short8, *(const u32x4*)(&Bs[(wn + nf * 16 + q15) * 40 + g * 8]));
#pragma unroll
        for (int mf = 0; mf < 4; ++mf)
#pragma unroll
            for (int nf = 0; nf < 4; ++nf)
                acc[mf][nf] = __builtin_amdgcn_mfma_f32_16x16x32_bf16(
                    af[mf], bf[nf], acc[mf][nf], 0, 0, 0);
        __syncthreads();
    }

#pragma unroll
    for (int mf = 0; mf < 4; ++mf)
#pragma unroll
        for (int nf = 0; nf < 4; ++nf)
#pragma unroll
            for (int r = 0; r < 4; ++r) {
                int m = m0 + wm + mf * 16 + 4 * g + r;
                int n = n0 + wn + nf * 16 + q15;
                float val = acc[mf][nf][r];
                if (OUTF32) {
                    ((float*)Out)[(size_t)m * Dn + n] = val;
                } else {
                    int b = m >> 11, s = m & (Sn - 1);
                    int h = n >> 6, dk = n & 63;
                    ((unsigned short*)Out)[(((size_t)(b * Hn + h) * Sn + s) << 6) +
                                           dk] = f2bf(val);
                }
            }
}

// ---------------------------------------------------------------------------
// Causal flash attention, DUAL-CHUNK blocks: block p owns q-chunks
// A = 31-p and B = p, processed in the SAME KV loop so both consume each
// staged KV tile (B active while j <= p). Compute balanced: (32-p)+(p+1)=33
// chunk-iterations per block; KV staged (32-p) times.
// NOTE: no min-waves in launch_bounds — the dual-chunk working set needs
// ~170 VGPRs; capping registers spills accumulators to scratch (R7: 456 MB
// scratch writes, 2.3x slowdown).
// ---------------------------------------------------------------------------
__global__ __launch_bounds__(256) void attn_fwd(
    const unsigned short* __restrict__ Qb, const unsigned short* __restrict__ Kb,
    const unsigned short* __restrict__ Vb, unsigned short* __restrict__ Xb) {
    __shared__ alignas(16) unsigned short Kt[64 * 64];
    __shared__ alignas(16) unsigned short Vt[64 * 64];

    constexpr float SCL = 0.18033688f;  // 0.125 * log2(e)

    const int tid = threadIdx.x;
    const int pair = blockIdx.x;  // 0..15
    const int bh = blockIdx.y;
    const int b = bh >> 4, h = bh & 15;
    const int lane = tid & 63, w = tid >> 6;
    const int g = lane >> 4, q15 = lane & 15;

    const unsigned short* Qh = Qb + (size_t)bh * Sn * DKn;
    const unsigned short* Kh = Kb + (size_t)bh * Sn * DKn;
    const unsigned short* Vh = Vb + (size_t)bh * Sn * DKn;

    const int st_row = tid >> 2, st_seg = tid & 3;  // K staging
    const int sv_kv = tid & 63, sv_g = tid >> 6;    // V staging
    const int sel = sv_kv & 1;
    const unsigned kvp = (unsigned)((sv_kv & ~1) * 2);  // byte col base in Vt

    const int jmaxA = NQB - 1 - pair;  // chunk A (long)
    const int jmaxB = pair;            // chunk B (short)
    const int qgA = jmaxA * 64 + w * 16 + q15;
    const int qgB = jmaxB * 64 + w * 16 + q15;

    short8 qfA[2], qfB[2];
#pragma unroll
    for (int ks = 0; ks < 2; ++ks) {
        qfA[ks] = __builtin_bit_cast(
            short8, *(const u32x4*)(Qh + (size_t)qgA * DKn + ks * 32 + g * 8));
        qfB[ks] = __builtin_bit_cast(
            short8, *(const u32x4*)(Qh + (size_t)qgB * DKn + ks * 32 + g * 8));
    }

    f32x4 xaccA[4] = {}, xaccB[4] = {};
    float mA = -1e30f, lA = 0.f, mB = -1e30f, lB = 0.f;

    u32x4 kr0, kr1, vr0, vr1;  // prefetch registers
    auto load_kv = [&](int j) {
        kr0 = *(const u32x4*)(Kh + (size_t)(j * 64 + st_row) * DKn + st_seg * 8);
        kr1 = *(const u32x4*)(Kh + (size_t)(j * 64 + st_row) * DKn +
                              (st_seg + 4) * 8);
        vr0 = *(const u32x4*)(Vh + (size_t)(j * 64 + sv_kv) * DKn + sv_g * 8);
        vr1 = *(const u32x4*)(Vh + (size_t)(j * 64 + sv_kv) * DKn + sv_g * 8 + 32);
    };

    // one chunk-iteration against the currently staged KV tile
    auto compute_chunk = [&](const short8 (&qf)[2], f32x4 (&xacc)[4],
                             float& m_run, float& l_run, int qg, int j,
                             bool diag) {
        // QK^T (swapped): sacc rows = kv, cols = q
        f32x4 sacc[4] = {};
#pragma unroll
        for (int mf = 0; mf < 4; ++mf) {
            int row = mf * 16 + q15;
#pragma unroll
            for (int ks = 0; ks < 2; ++ks) {
                unsigned byteoff = ((unsigned)(row * 128 + ks * 64 + g * 16)) ^
                                   ((unsigned)(row & 7) << 4);
                short8 kf =
                    __builtin_bit_cast(short8, *(const u32x4*)((char*)Kt + byteoff));
                sacc[mf] = __builtin_amdgcn_mfma_f32_16x16x32_bf16(kf, qf[ks],
                                                                   sacc[mf], 0, 0, 0);
            }
        }

        // mask + online softmax (log2 domain), lane owns q row qg
        float p[4][4];
        float pmax = -1e30f;
#pragma unroll
        for (int mf = 0; mf < 4; ++mf)
#pragma unroll
            for (int r = 0; r < 4; ++r) {
                float sv = sacc[mf][r] * SCL;
                if (diag) {
                    int kvg = j * 64 + mf * 16 + 4 * g + r;
                    if (kvg > qg) sv = -1e30f;
                }
                p[mf][r] = sv;
                pmax = fmaxf(pmax, sv);
            }
        pmax = fmaxf(pmax, __shfl_xor(pmax, 16));
        pmax = fmaxf(pmax, __shfl_xor(pmax, 32));
        if (__any(pmax > m_run + 8.f)) {  // T13 defer-max
            float mnew = fmaxf(m_run, pmax);
            float corr = exp2a(m_run - mnew);
            l_run *= corr;
#pragma unroll
            for (int mf = 0; mf < 4; ++mf)
#pragma unroll
                for (int r = 0; r < 4; ++r) xacc[mf][r] *= corr;
            m_run = mnew;
        }
        float lsum = 0.f;
#pragma unroll
        for (int mf = 0; mf < 4; ++mf)
#pragma unroll
            for (int r = 0; r < 4; ++r) {
                float e = exp2a(p[mf][r] - m_run);
                p[mf][r] = e;
                lsum += e;
            }
        lsum += __shfl_xor(lsum, 16);
        lsum += __shfl_xor(lsum, 32);
        l_run += lsum;

        // pack P pairs; PV as O^T = mfma(A=Vt, B=P^T)
        unsigned pkk[4][2];
#pragma unroll
        for (int mf = 0; mf < 4; ++mf) {
            pkk[mf][0] = pk2(p[mf][0], p[mf][1]);
            pkk[mf][1] = pk2(p[mf][2], p[mf][3]);
        }
#pragma unroll
        for (int ks = 0; ks < 2; ++ks) {
            unsigned bw[4];
#pragma unroll
            for (int w2 = 0; w2 < 4; ++w2) {
                // dest (g,q15) needs P[q15][kv=ks*32+g*8+2*w2,+1] =
                // pkk[2*ks+(g>>1)][w2&1] of lane g_src=2*(g&1)+(w2>>1).
                // Shuffle BOTH mf candidates (lane-invariant indices), select
                // on dest side (shfl evaluates on the SOURCE lane).
                int srcl = (2 * (g & 1) + (w2 >> 1)) * 16 + q15;
                unsigned v0 = (unsigned)__shfl((int)pkk[2 * ks][w2 & 1], srcl);
                unsigned v1 = (unsigned)__shfl((int)pkk[2 * ks + 1][w2 & 1], srcl);
                bw[w2] = (g & 2) ? v1 : v0;
            }
            u32x4 tmp = {bw[0], bw[1], bw[2], bw[3]};
            short8 pb = __builtin_bit_cast(short8, tmp);
#pragma unroll
            for (int mf = 0; mf < 4; ++mf) {
                int row = mf * 16 + q15;
                unsigned byteoff = ((unsigned)(row * 128 + ks * 64 + g * 16)) ^
                                   ((unsigned)(row & 7) << 4);
                short8 vf =
                    __builtin_bit_cast(short8, *(const u32x4*)((char*)Vt + byteoff));
                xacc[mf] = __builtin_amdgcn_mfma_f32_16x16x32_bf16(vf, pb,
                                                                   xacc[mf], 0, 0, 0);
            }
        }
    };

    load_kv(0);
    for (int j = 0; j <= jmaxA; ++j) {
        // ---- write staged KV regs to LDS ----
        {
            unsigned b0 = ((unsigned)(st_row * 128 + st_seg * 16)) ^
                          ((unsigned)(st_row & 7) << 4);
            unsigned b1 = ((unsigned)(st_row * 128 + (st_seg + 4) * 16)) ^
                          ((unsigned)(st_row & 7) << 4);
            *(u32x4*)((char*)Kt + b0) = kr0;
            *(u32x4*)((char*)Kt + b1) = kr1;
        }
#pragma unroll
        for (int r2 = 0; r2 < 2; ++r2) {
            u32x4 vvec = r2 ? vr1 : vr0;
            int dk0 = sv_g * 8 + r2 * 32;
#pragma unroll
            for (int i = 0; i < 4; ++i) {
                unsigned mine = vvec[i];
                unsigned theirs = (unsigned)__shfl_xor((int)mine, 1);
                int dk_abs = dk0 + 2 * i + sel;
                unsigned out = sel ? ((theirs >> 16) | (mine & 0xffff0000u))
                                   : ((mine & 0xffffu) | (theirs << 16));
                unsigned byteoff = ((unsigned)(dk_abs * 128) + kvp) ^
                                   ((unsigned)(dk_abs & 7) << 4);
                *(unsigned*)((char*)Vt + byteoff) = out;
            }
        }
        __syncthreads();

        // next tile's loads in flight under the compute
        if (j < jmaxA) load_kv(j + 1);

        compute_chunk(qfA, xaccA, mA, lA, qgA, j, j == jmaxA);
        if (j <= jmaxB) compute_chunk(qfB, xaccB, mB, lB, qgB, j, j == jmaxB);

        __syncthreads();
    }

    // ---- epilogue: lane owns q=q15 row of each chunk; 4x 8B stores ----
    {
        float inv = 1.0f / lA;
        size_t rowbase =
            (size_t)(b * Sn + jmaxA * 64 + w * 16 + q15) * Dn + h * 64;
#pragma unroll
        for (int mf = 0; mf < 4; ++mf) {
            unsigned w0 = pk2(xaccA[mf][0] * inv, xaccA[mf][1] * inv);
            unsigned w1 = pk2(xaccA[mf][2] * inv, xaccA[mf][3] * inv);
            uint2 val = {w0, w1};
            *(uint2*)(Xb + rowbase + mf * 16 + 4 * g) = val;
        }
    }
    {
        float inv = 1.0f / lB;
        size_t rowbase =
            (size_t)(b * Sn + jmaxB * 64 + w * 16 + q15) * Dn + h * 64;
#pragma unroll
        for (int mf = 0; mf < 4; ++mf) {
            unsigned w0 = pk2(xaccB[mf][0] * inv, xaccB[mf][1] * inv);
            unsigned w1 = pk2(xaccB[mf][2] * inv, xaccB[mf][3] * inv);
            uint2 val = {w0, w1};
            *(uint2*)(Xb + rowbase + mf * 16 + 4 * g) = val;
        }
    }
}

// ---------------------------------------------------------------------------
// Launch. ws layout (bf16): Qb | Kb | Vb | Xb (16 MiB each) | Wb (8 MiB,
// 4 weight matrices bf16, if ws_size permits).
// ---------------------------------------------------------------------------
extern "C" void kernel_launch(void* const* d_in, const int* in_sizes, int n_in,
                              void* d_out, int out_size, void* d_ws, size_t ws_size,
                              hipStream_t stream) {
    (void)in_sizes; (void)n_in; (void)out_size;
    const float* q = (const float*)d_in[0];
    const float* k = (const float*)d_in[1];
    const float* v = (const float*)d_in[2];
    // d_in[3] = mask (causal tril; implemented analytically)
    const float* Wq = (const float*)d_in[4];
    const float* Wk = (const float*)d_in[5];
    const float* Wv = (const float*)d_in[6];
    const float* Wo = (const float*)d_in[7];

    unsigned short* Qb = (unsigned short*)d_ws;
    unsigned short* Kb = Qb + (size_t)Mrows * Dn;
    unsigned short* Vb = Kb + (size_t)Mrows * Dn;
    unsigned short* Xb = Vb + (size_t)Mrows * Dn;
    unsigned short* Wb = Xb + (size_t)Mrows * Dn;

    const size_t needW =
        (size_t)4 * Mrows * Dn * 2 + (size_t)4 * Dn * Dn * 2;  // 64 + 8 MiB
    const bool useWb = ws_size >= needW;

    dim3 blk(256);
    dim3 ggrid(Dn / 128, Mrows / 128);

    if (useWb) {
        cvt_w<<<dim3(Dn * Dn / (256 * 8), 4), blk, 0, stream>>>(Wq, Wk, Wv, Wo, Wb);
        const unsigned short* Wqb = Wb;
        const unsigned short* Wkb = Wb + (size_t)Dn * Dn;
        const unsigned short* Wvb = Wb + (size_t)2 * Dn * Dn;
        const unsigned short* Wob = Wb + (size_t)3 * Dn * Dn;
        gemm_nt<false, true, false><<<ggrid, blk, 0, stream>>>(q, Wqb, Qb);
        gemm_nt<false, true, false><<<ggrid, blk, 0, stream>>>(k, Wkb, Kb);
        gemm_nt<false, true, false><<<ggrid, blk, 0, stream>>>(v, Wvb, Vb);
        attn_fwd<<<dim3(NQB / 2, Bn * Hn), blk, 0, stream>>>(Qb, Kb, Vb, Xb);
        gemm_nt<true, true, true><<<ggrid, blk, 0, stream>>>(Xb, Wob, d_out);
    } else {
        gemm_nt<false, false, false><<<ggrid, blk, 0, stream>>>(q, Wq, Qb);
        gemm_nt<false, false, false><<<ggrid, blk, 0, stream>>>(k, Wk, Kb);
        gemm_nt<false, false, false><<<ggrid, blk, 0, stream>>>(v, Wv, Vb);
        attn_fwd<<<dim3(NQB / 2, Bn * Hn), blk, 0, stream>>>(Qb, Kb, Vb, Xb);
        gemm_nt<true, false, true><<<ggrid, blk, 0, stream>>>(Xb, Wo, d_out);
    }
}

// Round 10
// 282.499 us; speedup vs baseline: 1.7429x; 1.0088x over previous
//
#include <hip/hip_runtime.h>
#include <hip/hip_bf16.h>

// Problem constants
constexpr int Bn = 4, Sn = 2048, Dn = 1024, Hn = 16, DKn = 64;
constexpr int Mrows = Bn * Sn;  // 8192
constexpr int NQB = Sn / 64;    // 32 q-chunks of 64 rows

typedef __attribute__((ext_vector_type(8))) short short8;
typedef __attribute__((ext_vector_type(4))) float f32x4;
typedef __attribute__((ext_vector_type(4))) unsigned int u32x4;

#define DEV __device__ __forceinline__

// fp32 -> bf16 RNE, scalar (epilogue scatter only)
DEV unsigned short f2bf(float f) {
    unsigned u = __builtin_bit_cast(unsigned, f);
    u += 0x7FFFu + ((u >> 16) & 1u);
    return (unsigned short)(u >> 16);
}
// fp32 pair -> packed bf16x2 via v_cvt_pk_bf16_f32 (hardware RNE)
DEV unsigned pk2(float a, float b) {
    __hip_bfloat162 h = __float22bfloat162_rn(float2{a, b});
    unsigned u;
    __builtin_memcpy(&u, &h, 4);
    return u;
}
// 2^x via v_exp_f32
DEV float exp2a(float x) {
    float r;
    asm("v_exp_f32 %0, %1" : "=v"(r) : "v"(x));
    return r;
}

// ---------------------------------------------------------------------------
// Weights fp32 -> bf16, one matrix per blockIdx.y. 8 elems/thread.
// ---------------------------------------------------------------------------
__global__ __launch_bounds__(256) void cvt_w(const float* __restrict__ W0,
                                             const float* __restrict__ W1,
                                             const float* __restrict__ W2,
                                             const float* __restrict__ W3,
                                             unsigned short* __restrict__ Out) {
    const float* src = blockIdx.y == 0 ? W0
                     : blockIdx.y == 1 ? W1
                     : blockIdx.y == 2 ? W2 : W3;
    size_t off = ((size_t)blockIdx.x * 256 + threadIdx.x) * 8;
    const float4* s = (const float4*)(src + off);
    float4 a = s[0], b = s[1];
    u32x4 p = {pk2(a.x, a.y), pk2(a.z, a.w), pk2(b.x, b.y), pk2(b.z, b.w)};
    *(u32x4*)(Out + (size_t)blockIdx.y * (Dn * Dn) + off) = p;
}

// ---------------------------------------------------------------------------
// GEMM body: C[m,n] = sum_k A[m,k] * W[n,k]  (y = x @ W^T), M=8192, N=K=1024.
// 128x128 tile, BK=32, 256 threads (4 waves, 2x2 wave grid, 64x64 per wave).
// Reg-prefetch of next K-step during compute. A/B optionally bf16.
// ---------------------------------------------------------------------------
template <bool ABF16, bool BBF16, bool OUTF32>
DEV void gemm_body(const void* __restrict__ Ap, const void* __restrict__ Bw,
                   void* __restrict__ Out) {
    __shared__ alignas(16) unsigned short As[128 * 40];
    __shared__ alignas(16) unsigned short Bs[128 * 40];

    const int tid = threadIdx.x;
    const int n0 = blockIdx.x * 128;
    const int m0 = blockIdx.y * 128;
    const int lane = tid & 63;
    const int w = tid >> 6;
    const int wm = (w >> 1) * 64, wn = (w & 1) * 64;
    const int g = lane >> 4, q15 = lane & 15;

    f32x4 acc[4][4] = {};

    const int srow = tid >> 1, shalf = tid & 1;

    const float* Af = (const float*)Ap;
    const unsigned short* Ab = (const unsigned short*)Ap;
    const float* Bf = (const float*)Bw;
    const unsigned short* Bb = (const unsigned short*)Bw;

    float4 fa0, fa1, fa2, fa3, fb0, fb1, fb2, fb3;
    u32x4 ua0, ua1, ub0, ub1;

    auto loadA = [&](int kk) {
        if constexpr (ABF16) {
            const u32x4* s =
                (const u32x4*)(Ab + (size_t)(m0 + srow) * Dn + kk + shalf * 16);
            ua0 = s[0];
            ua1 = s[1];
        } else {
            const float4* s =
                (const float4*)(Af + (size_t)(m0 + srow) * Dn + kk + shalf * 16);
            fa0 = s[0]; fa1 = s[1]; fa2 = s[2]; fa3 = s[3];
        }
    };
    auto loadB = [&](int kk) {
        if constexpr (BBF16) {
            const u32x4* s =
                (const u32x4*)(Bb + (size_t)(n0 + srow) * Dn + kk + shalf * 16);
            ub0 = s[0];
            ub1 = s[1];
        } else {
            const float4* s =
                (const float4*)(Bf + (size_t)(n0 + srow) * Dn + kk + shalf * 16);
            fb0 = s[0]; fb1 = s[1]; fb2 = s[2]; fb3 = s[3];
        }
    };
    auto store = [&]() {
        u32x4* da = (u32x4*)(&As[srow * 40 + shalf * 16]);
        if constexpr (ABF16) {
            da[0] = ua0;
            da[1] = ua1;
        } else {
            u32x4 p0 = {pk2(fa0.x, fa0.y), pk2(fa0.z, fa0.w), pk2(fa1.x, fa1.y),
                        pk2(fa1.z, fa1.w)};
            u32x4 p1 = {pk2(fa2.x, fa2.y), pk2(fa2.z, fa2.w), pk2(fa3.x, fa3.y),
                        pk2(fa3.z, fa3.w)};
            da[0] = p0;
            da[1] = p1;
        }
        u32x4* db = (u32x4*)(&Bs[srow * 40 + shalf * 16]);
        if constexpr (BBF16) {
            db[0] = ub0;
            db[1] = ub1;
        } else {
            u32x4 q0 = {pk2(fb0.x, fb0.y), pk2(fb0.z, fb0.w), pk2(fb1.x, fb1.y),
                        pk2(fb1.z, fb1.w)};
            u32x4 q1 = {pk2(fb2.x, fb2.y), pk2(fb2.z, fb2.w), pk2(fb3.x, fb3.y),
                        pk2(fb3.z, fb3.w)};
            db[0] = q0;
            db[1] = q1;
        }
    };

    loadA(0);
    loadB(0);
    for (int kk = 0; kk < Dn; kk += 32) {
        store();
        __syncthreads();
        if (kk + 32 < Dn) {
            loadA(kk + 32);
            loadB(kk + 32);
        }

        short8 af[4], bf[4];
#pragma unroll
        for (int mf = 0; mf < 4; ++mf)
            af[mf] = __builtin_bit_cast(
                short8, *(const u32x4*)(&As[(wm + mf * 16 + q15) * 40 + g * 8]));
#pragma unroll
        for (int nf = 0; nf < 4; ++nf)
            bf[nf] = __builtin_bit_cast(
                short8, *(const u32x4*)(&Bs[(wn + nf * 16 + q15) * 40 + g * 8]));
#pragma unroll
        for (int mf = 0; mf < 4; ++mf)
#pragma unroll
            for (int nf = 0; nf < 4; ++nf)
                acc[mf][nf] = __builtin_amdgcn_mfma_f32_16x16x32_bf16(
                    af[mf], bf[nf], acc[mf][nf], 0, 0, 0);
        __syncthreads();
    }

#pragma unroll
    for (int mf = 0; mf < 4; ++mf)
#pragma unroll
        for (int nf = 0; nf < 4; ++nf)
#pragma unroll
            for (int r = 0; r < 4; ++r) {
                int m = m0 + wm + mf * 16 + 4 * g + r;
                int n = n0 + wn + nf * 16 + q15;
                float val = acc[mf][nf][r];
                if (OUTF32) {
                    ((float*)Out)[(size_t)m * Dn + n] = val;
                } else {
                    int b = m >> 11, s = m & (Sn - 1);
                    int h = n >> 6, dk = n & 63;
                    ((unsigned short*)Out)[(((size_t)(b * Hn + h) * Sn + s) << 6) +
                                           dk] = f2bf(val);
                }
            }
}

template <bool ABF16, bool BBF16, bool OUTF32>
__global__ __launch_bounds__(256) void gemm_nt(const void* __restrict__ Ap,
                                               const void* __restrict__ Bw,
                                               void* __restrict__ Out) {
    gemm_body<ABF16, BBF16, OUTF32>(Ap, Bw, Out);
}

// Fused QKV projection: grid.z selects {q,k,v}. 1536 blocks -> 6 blocks/CU
// (3 separate launches were 512 blocks = 2/CU = latency-starved).
__global__ __launch_bounds__(256) void gemm_qkv(
    const float* __restrict__ q, const float* __restrict__ k,
    const float* __restrict__ v, const unsigned short* __restrict__ Wb,
    unsigned short* __restrict__ Qb, unsigned short* __restrict__ Kb,
    unsigned short* __restrict__ Vb) {
    const int z = blockIdx.z;
    const void* A = z == 0 ? (const void*)q : z == 1 ? (const void*)k
                                                     : (const void*)v;
    const void* Bw = (const void*)(Wb + (size_t)z * Dn * Dn);
    void* Out = z == 0 ? (void*)Qb : z == 1 ? (void*)Kb : (void*)Vb;
    gemm_body<false, true, false>(A, Bw, Out);
}

// ---------------------------------------------------------------------------
// Causal flash attention, load-balanced pairs: block p runs chunk 31-p then
// chunk p sequentially (uniform 33 KV-iterations). 256 threads = 4 waves,
// each wave owns 16 q rows. DOUBLE-BUFFERED LDS (Kt/Vt x2, 32 KiB): one
// barrier per iteration — iter j: issue loads(j+1) -> compute from buf[j&1]
// -> write regs to buf[(j+1)&1] -> barrier. Writes go to the opposite
// buffer, so the single end-of-iter barrier orders all reads before
// overwrites (incl. across the hp boundary).
// Kt: [64kv][64dk] XOR-swizzled; Vt: [64dk][64kv] transposed (kv-pair shfl
// trick). QK^T and PV operand-swapped; softmax log2-domain + T13 defer-max.
// NOTE: no min-waves in launch_bounds (R7: register cap -> 456MB spill).
// ---------------------------------------------------------------------------
__global__ __launch_bounds__(256) void attn_fwd(
    const unsigned short* __restrict__ Qb, const unsigned short* __restrict__ Kb,
    const unsigned short* __restrict__ Vb, unsigned short* __restrict__ Xb) {
    __shared__ alignas(16) unsigned short Kt[2][64 * 64];
    __shared__ alignas(16) unsigned short Vt[2][64 * 64];

    constexpr float SCL = 0.18033688f;  // 0.125 * log2(e)

    const int tid = threadIdx.x;
    const int pair = blockIdx.x;  // 0..15
    const int bh = blockIdx.y;
    const int b = bh >> 4, h = bh & 15;
    const int lane = tid & 63, w = tid >> 6;
    const int g = lane >> 4, q15 = lane & 15;

    const unsigned short* Qh = Qb + (size_t)bh * Sn * DKn;
    const unsigned short* Kh = Kb + (size_t)bh * Sn * DKn;
    const unsigned short* Vh = Vb + (size_t)bh * Sn * DKn;

    const int st_row = tid >> 2, st_seg = tid & 3;  // K staging
    const int sv_kv = tid & 63, sv_g = tid >> 6;    // V staging
    const int sel = sv_kv & 1;
    const unsigned kvp = (unsigned)((sv_kv & ~1) * 2);  // byte col base in Vt

    u32x4 kr0, kr1, vr0, vr1;  // prefetch registers
    auto load_kv = [&](int j) {
        kr0 = *(const u32x4*)(Kh + (size_t)(j * 64 + st_row) * DKn + st_seg * 8);
        kr1 = *(const u32x4*)(Kh + (size_t)(j * 64 + st_row) * DKn +
                              (st_seg + 4) * 8);
        vr0 = *(const u32x4*)(Vh + (size_t)(j * 64 + sv_kv) * DKn + sv_g * 8);
        vr1 = *(const u32x4*)(Vh + (size_t)(j * 64 + sv_kv) * DKn + sv_g * 8 + 32);
    };
    auto write_tile = [&](int c) {
        char* kb = (char*)&Kt[c][0];
        char* vb = (char*)&Vt[c][0];
        unsigned b0 = ((unsigned)(st_row * 128 + st_seg * 16)) ^
                      ((unsigned)(st_row & 7) << 4);
        unsigned b1 = ((unsigned)(st_row * 128 + (st_seg + 4) * 16)) ^
                      ((unsigned)(st_row & 7) << 4);
        *(u32x4*)(kb + b0) = kr0;
        *(u32x4*)(kb + b1) = kr1;
#pragma unroll
        for (int r2 = 0; r2 < 2; ++r2) {
            u32x4 vvec = r2 ? vr1 : vr0;
            int dk0 = sv_g * 8 + r2 * 32;
#pragma unroll
            for (int i = 0; i < 4; ++i) {
                unsigned mine = vvec[i];
                unsigned theirs = (unsigned)__shfl_xor((int)mine, 1);
                int dk_abs = dk0 + 2 * i + sel;
                unsigned out = sel ? ((theirs >> 16) | (mine & 0xffff0000u))
                                   : ((mine & 0xffffu) | (theirs << 16));
                unsigned byteoff = ((unsigned)(dk_abs * 128) + kvp) ^
                                   ((unsigned)(dk_abs & 7) << 4);
                *(unsigned*)(vb + byteoff) = out;
            }
        }
    };

    for (int hp = 0; hp < 2; ++hp) {
        const int qblk = hp == 0 ? (NQB - 1 - pair) : pair;
        const int qg = qblk * 64 + w * 16 + q15;  // this lane's q row

        short8 qf[2];
#pragma unroll
        for (int ks = 0; ks < 2; ++ks)
            qf[ks] = __builtin_bit_cast(
                short8, *(const u32x4*)(Qh + (size_t)qg * DKn + ks * 32 + g * 8));

        f32x4 xacc[4] = {};  // O^T: xacc[mf][r] = O[q=q15][d=mf*16+4g+r]
        float m_run = -1e30f, l_run = 0.f;

        load_kv(0);
        write_tile(0);
        __syncthreads();

        for (int j = 0; j <= qblk; ++j) {
            if (j < qblk) load_kv(j + 1);  // in flight over this compute

            const char* kb = (const char*)&Kt[j & 1][0];
            const char* vb = (const char*)&Vt[j & 1][0];

            // ---- QK^T (swapped): sacc rows = kv, cols = q ----
            f32x4 sacc[4] = {};
#pragma unroll
            for (int mf = 0; mf < 4; ++mf) {
                int row = mf * 16 + q15;
#pragma unroll
                for (int ks = 0; ks < 2; ++ks) {
                    unsigned byteoff = ((unsigned)(row * 128 + ks * 64 + g * 16)) ^
                                       ((unsigned)(row & 7) << 4);
                    short8 kf = __builtin_bit_cast(
                        short8, *(const u32x4*)(kb + byteoff));
                    sacc[mf] = __builtin_amdgcn_mfma_f32_16x16x32_bf16(
                        kf, qf[ks], sacc[mf], 0, 0, 0);
                }
            }

            // ---- mask + online softmax (log2 domain), lane owns q row qg ----
            float p[4][4];
            float pmax = -1e30f;
            const bool diag = (j == qblk);
#pragma unroll
            for (int mf = 0; mf < 4; ++mf)
#pragma unroll
                for (int r = 0; r < 4; ++r) {
                    float sv = sacc[mf][r] * SCL;
                    if (diag) {
                        int kvg = j * 64 + mf * 16 + 4 * g + r;
                        if (kvg > qg) sv = -1e30f;
                    }
                    p[mf][r] = sv;
                    pmax = fmaxf(pmax, sv);
                }
            pmax = fmaxf(pmax, __shfl_xor(pmax, 16));
            pmax = fmaxf(pmax, __shfl_xor(pmax, 32));
            if (__any(pmax > m_run + 8.f)) {  // T13 defer-max
                float mnew = fmaxf(m_run, pmax);
                float corr = exp2a(m_run - mnew);
                l_run *= corr;
#pragma unroll
                for (int mf = 0; mf < 4; ++mf)
#pragma unroll
                    for (int r = 0; r < 4; ++r) xacc[mf][r] *= corr;
                m_run = mnew;
            }
            float lsum = 0.f;
#pragma unroll
            for (int mf = 0; mf < 4; ++mf)
#pragma unroll
                for (int r = 0; r < 4; ++r) {
                    float e = exp2a(p[mf][r] - m_run);
                    p[mf][r] = e;
                    lsum += e;
                }
            lsum += __shfl_xor(lsum, 16);
            lsum += __shfl_xor(lsum, 32);
            l_run += lsum;

            // ---- pack P pairs; PV as O^T = mfma(A=Vt, B=P^T) ----
            unsigned pkk[4][2];
#pragma unroll
            for (int mf = 0; mf < 4; ++mf) {
                pkk[mf][0] = pk2(p[mf][0], p[mf][1]);
                pkk[mf][1] = pk2(p[mf][2], p[mf][3]);
            }
#pragma unroll
            for (int ks = 0; ks < 2; ++ks) {
                unsigned bw[4];
#pragma unroll
                for (int w2 = 0; w2 < 4; ++w2) {
                    // dest (g,q15) needs P[q15][kv=ks*32+g*8+2*w2,+1] =
                    // pkk[2*ks+(g>>1)][w2&1] of lane g_src=2*(g&1)+(w2>>1).
                    // Shuffle BOTH mf candidates (lane-invariant indices),
                    // select on dest side (shfl evaluates on the SOURCE lane).
                    int srcl = (2 * (g & 1) + (w2 >> 1)) * 16 + q15;
                    unsigned v0 = (unsigned)__shfl((int)pkk[2 * ks][w2 & 1], srcl);
                    unsigned v1 =
                        (unsigned)__shfl((int)pkk[2 * ks + 1][w2 & 1], srcl);
                    bw[w2] = (g & 2) ? v1 : v0;
                }
                u32x4 tmp = {bw[0], bw[1], bw[2], bw[3]};
                short8 pb = __builtin_bit_cast(short8, tmp);
#pragma unroll
                for (int mf = 0; mf < 4; ++mf) {
                    int row = mf * 16 + q15;
                    unsigned byteoff = ((unsigned)(row * 128 + ks * 64 + g * 16)) ^
                                       ((unsigned)(row & 7) << 4);
                    short8 vf = __builtin_bit_cast(
                        short8, *(const u32x4*)(vb + byteoff));
                    xacc[mf] = __builtin_amdgcn_mfma_f32_16x16x32_bf16(
                        vf, pb, xacc[mf], 0, 0, 0);
                }
            }

            if (j < qblk) write_tile((j + 1) & 1);
            __syncthreads();
        }

        // ---- epilogue: lane owns q=q15 row; 4x 8B stores ----
        float inv = 1.0f / l_run;
        size_t rowbase = (size_t)(b * Sn + qblk * 64 + w * 16 + q15) * Dn + h * 64;
#pragma unroll
        for (int mf = 0; mf < 4; ++mf) {
            unsigned w0 = pk2(xacc[mf][0] * inv, xacc[mf][1] * inv);
            unsigned w1 = pk2(xacc[mf][2] * inv, xacc[mf][3] * inv);
            uint2 val = {w0, w1};
            *(uint2*)(Xb + rowbase + mf * 16 + 4 * g) = val;
        }
    }
}

// ---------------------------------------------------------------------------
// Launch. ws layout (bf16): Qb | Kb | Vb | Xb (16 MiB each) | Wb (8 MiB,
// 4 weight matrices bf16, if ws_size permits).
// ---------------------------------------------------------------------------
extern "C" void kernel_launch(void* const* d_in, const int* in_sizes, int n_in,
                              void* d_out, int out_size, void* d_ws, size_t ws_size,
                              hipStream_t stream) {
    (void)in_sizes; (void)n_in; (void)out_size;
    const float* q = (const float*)d_in[0];
    const float* k = (const float*)d_in[1];
    const float* v = (const float*)d_in[2];
    // d_in[3] = mask (causal tril; implemented analytically)
    const float* Wq = (const float*)d_in[4];
    const float* Wk = (const float*)d_in[5];
    const float* Wv = (const float*)d_in[6];
    const float* Wo = (const float*)d_in[7];

    unsigned short* Qb = (unsigned short*)d_ws;
    unsigned short* Kb = Qb + (size_t)Mrows * Dn;
    unsigned short* Vb = Kb + (size_t)Mrows * Dn;
    unsigned short* Xb = Vb + (size_t)Mrows * Dn;
    unsigned short* Wb = Xb + (size_t)Mrows * Dn;

    const size_t needW =
        (size_t)4 * Mrows * Dn * 2 + (size_t)4 * Dn * Dn * 2;  // 64 + 8 MiB
    const bool useWb = ws_size >= needW;

    dim3 blk(256);
    dim3 ggrid(Dn / 128, Mrows / 128);

    if (useWb) {
        cvt_w<<<dim3(Dn * Dn / (256 * 8), 4), blk, 0, stream>>>(Wq, Wk, Wv, Wo, Wb);
        gemm_qkv<<<dim3(Dn / 128, Mrows / 128, 3), blk, 0, stream>>>(q, k, v, Wb,
                                                                     Qb, Kb, Vb);
        attn_fwd<<<dim3(NQB / 2, Bn * Hn), blk, 0, stream>>>(Qb, Kb, Vb, Xb);
        gemm_nt<true, true, true><<<ggrid, blk, 0, stream>>>(
            Xb, Wb + (size_t)3 * Dn * Dn, d_out);
    } else {
        gemm_nt<false, false, false><<<ggrid, blk, 0, stream>>>(q, Wq, Qb);
        gemm_nt<false, false, false><<<ggrid, blk, 0, stream>>>(k, Wk, Kb);
        gemm_nt<false, false, false><<<ggrid, blk, 0, stream>>>(v, Wv, Vb);
        attn_fwd<<<dim3(NQB / 2, Bn * Hn), blk, 0, stream>>>(Qb, Kb, Vb, Xb);
        gemm_nt<true, false, true><<<ggrid, blk, 0, stream>>>(Xb, Wo, d_out);
    }
}

// Round 11
// 252.673 us; speedup vs baseline: 1.9486x; 1.1180x over previous
//
#include <hip/hip_runtime.h>
#include <hip/hip_bf16.h>

// Problem constants
constexpr int Bn = 4, Sn = 2048, Dn = 1024, Hn = 16, DKn = 64;
constexpr int Mrows = Bn * Sn;  // 8192
constexpr int NQB = Sn / 64;    // 32 q-chunks of 64 rows

typedef __attribute__((ext_vector_type(8))) short short8;
typedef __attribute__((ext_vector_type(4))) float f32x4;
typedef __attribute__((ext_vector_type(4))) unsigned int u32x4;

#define DEV __device__ __forceinline__

// fp32 -> bf16 RNE, scalar (epilogue scatter only)
DEV unsigned short f2bf(float f) {
    unsigned u = __builtin_bit_cast(unsigned, f);
    u += 0x7FFFu + ((u >> 16) & 1u);
    return (unsigned short)(u >> 16);
}
// fp32 pair -> packed bf16x2 via v_cvt_pk_bf16_f32 (hardware RNE)
DEV unsigned pk2(float a, float b) {
    __hip_bfloat162 h = __float22bfloat162_rn(float2{a, b});
    unsigned u;
    __builtin_memcpy(&u, &h, 4);
    return u;
}
// 2^x via v_exp_f32
DEV float exp2a(float x) {
    float r;
    asm("v_exp_f32 %0, %1" : "=v"(r) : "v"(x));
    return r;
}

// ---------------------------------------------------------------------------
// Weights fp32 -> bf16, one matrix per blockIdx.y. 8 elems/thread.
// ---------------------------------------------------------------------------
__global__ __launch_bounds__(256) void cvt_w(const float* __restrict__ W0,
                                             const float* __restrict__ W1,
                                             const float* __restrict__ W2,
                                             const float* __restrict__ W3,
                                             unsigned short* __restrict__ Out) {
    const float* src = blockIdx.y == 0 ? W0
                     : blockIdx.y == 1 ? W1
                     : blockIdx.y == 2 ? W2 : W3;
    size_t off = ((size_t)blockIdx.x * 256 + threadIdx.x) * 8;
    const float4* s = (const float4*)(src + off);
    float4 a = s[0], b = s[1];
    u32x4 p = {pk2(a.x, a.y), pk2(a.z, a.w), pk2(b.x, b.y), pk2(b.z, b.w)};
    *(u32x4*)(Out + (size_t)blockIdx.y * (Dn * Dn) + off) = p;
}

// ---------------------------------------------------------------------------
// GEMM body: C[m,n] = sum_k A[m,k] * W[n,k]  (y = x @ W^T), M=8192, N=K=1024.
// 128x128 tile, BK=32, 256 threads (4 waves, 2x2 wave grid, 64x64 per wave).
// Reg-prefetch of next K-step during compute. A/B optionally bf16.
// ---------------------------------------------------------------------------
template <bool ABF16, bool BBF16, bool OUTF32>
DEV void gemm_body(const void* __restrict__ Ap, const void* __restrict__ Bw,
                   void* __restrict__ Out) {
    __shared__ alignas(16) unsigned short As[128 * 40];
    __shared__ alignas(16) unsigned short Bs[128 * 40];

    const int tid = threadIdx.x;
    const int n0 = blockIdx.x * 128;
    const int m0 = blockIdx.y * 128;
    const int lane = tid & 63;
    const int w = tid >> 6;
    const int wm = (w >> 1) * 64, wn = (w & 1) * 64;
    const int g = lane >> 4, q15 = lane & 15;

    f32x4 acc[4][4] = {};

    const int srow = tid >> 1, shalf = tid & 1;

    const float* Af = (const float*)Ap;
    const unsigned short* Ab = (const unsigned short*)Ap;
    const float* Bf = (const float*)Bw;
    const unsigned short* Bb = (const unsigned short*)Bw;

    float4 fa0, fa1, fa2, fa3, fb0, fb1, fb2, fb3;
    u32x4 ua0, ua1, ub0, ub1;

    auto loadA = [&](int kk) {
        if constexpr (ABF16) {
            const u32x4* s =
                (const u32x4*)(Ab + (size_t)(m0 + srow) * Dn + kk + shalf * 16);
            ua0 = s[0];
            ua1 = s[1];
        } else {
            const float4* s =
                (const float4*)(Af + (size_t)(m0 + srow) * Dn + kk + shalf * 16);
            fa0 = s[0]; fa1 = s[1]; fa2 = s[2]; fa3 = s[3];
        }
    };
    auto loadB = [&](int kk) {
        if constexpr (BBF16) {
            const u32x4* s =
                (const u32x4*)(Bb + (size_t)(n0 + srow) * Dn + kk + shalf * 16);
            ub0 = s[0];
            ub1 = s[1];
        } else {
            const float4* s =
                (const float4*)(Bf + (size_t)(n0 + srow) * Dn + kk + shalf * 16);
            fb0 = s[0]; fb1 = s[1]; fb2 = s[2]; fb3 = s[3];
        }
    };
    auto store = [&]() {
        u32x4* da = (u32x4*)(&As[srow * 40 + shalf * 16]);
        if constexpr (ABF16) {
            da[0] = ua0;
            da[1] = ua1;
        } else {
            u32x4 p0 = {pk2(fa0.x, fa0.y), pk2(fa0.z, fa0.w), pk2(fa1.x, fa1.y),
                        pk2(fa1.z, fa1.w)};
            u32x4 p1 = {pk2(fa2.x, fa2.y), pk2(fa2.z, fa2.w), pk2(fa3.x, fa3.y),
                        pk2(fa3.z, fa3.w)};
            da[0] = p0;
            da[1] = p1;
        }
        u32x4* db = (u32x4*)(&Bs[srow * 40 + shalf * 16]);
        if constexpr (BBF16) {
            db[0] = ub0;
            db[1] = ub1;
        } else {
            u32x4 q0 = {pk2(fb0.x, fb0.y), pk2(fb0.z, fb0.w), pk2(fb1.x, fb1.y),
                        pk2(fb1.z, fb1.w)};
            u32x4 q1 = {pk2(fb2.x, fb2.y), pk2(fb2.z, fb2.w), pk2(fb3.x, fb3.y),
                        pk2(fb3.z, fb3.w)};
            db[0] = q0;
            db[1] = q1;
        }
    };

    loadA(0);
    loadB(0);
    for (int kk = 0; kk < Dn; kk += 32) {
        store();
        __syncthreads();
        if (kk + 32 < Dn) {
            loadA(kk + 32);
            loadB(kk + 32);
        }

        short8 af[4], bf[4];
#pragma unroll
        for (int mf = 0; mf < 4; ++mf)
            af[mf] = __builtin_bit_cast(
                short8, *(const u32x4*)(&As[(wm + mf * 16 + q15) * 40 + g * 8]));
#pragma unroll
        for (int nf = 0; nf < 4; ++nf)
            bf[nf] = __builtin_bit_cast(
                short8, *(const u32x4*)(&Bs[(wn + nf * 16 + q15) * 40 + g * 8]));
#pragma unroll
        for (int mf = 0; mf < 4; ++mf)
#pragma unroll
            for (int nf = 0; nf < 4; ++nf)
                acc[mf][nf] = __builtin_amdgcn_mfma_f32_16x16x32_bf16(
                    af[mf], bf[nf], acc[mf][nf], 0, 0, 0);
        __syncthreads();
    }

#pragma unroll
    for (int mf = 0; mf < 4; ++mf)
#pragma unroll
        for (int nf = 0; nf < 4; ++nf)
#pragma unroll
            for (int r = 0; r < 4; ++r) {
                int m = m0 + wm + mf * 16 + 4 * g + r;
                int n = n0 + wn + nf * 16 + q15;
                float val = acc[mf][nf][r];
                if (OUTF32) {
                    ((float*)Out)[(size_t)m * Dn + n] = val;
                } else {
                    int b = m >> 11, s = m & (Sn - 1);
                    int h = n >> 6, dk = n & 63;
                    ((unsigned short*)Out)[(((size_t)(b * Hn + h) * Sn + s) << 6) +
                                           dk] = f2bf(val);
                }
            }
}

template <bool ABF16, bool BBF16, bool OUTF32>
__global__ __launch_bounds__(256) void gemm_nt(const void* __restrict__ Ap,
                                               const void* __restrict__ Bw,
                                               void* __restrict__ Out) {
    gemm_body<ABF16, BBF16, OUTF32>(Ap, Bw, Out);
}

// Fused QKV projection: grid.z selects {q,k,v}. 1536 blocks -> 6 blocks/CU.
__global__ __launch_bounds__(256) void gemm_qkv(
    const float* __restrict__ q, const float* __restrict__ k,
    const float* __restrict__ v, const unsigned short* __restrict__ Wb,
    unsigned short* __restrict__ Qb, unsigned short* __restrict__ Kb,
    unsigned short* __restrict__ Vb) {
    const int z = blockIdx.z;
    const void* A = z == 0 ? (const void*)q : z == 1 ? (const void*)k
                                                     : (const void*)v;
    const void* Bw = (const void*)(Wb + (size_t)z * Dn * Dn);
    void* Out = z == 0 ? (void*)Qb : z == 1 ? (void*)Kb : (void*)Vb;
    gemm_body<false, true, false>(A, Bw, Out);
}

// ---------------------------------------------------------------------------
// Causal flash attention, load-balanced pairs: block p runs chunk 31-p then
// chunk p (uniform 33 KV-iterations). 256 threads = 4 waves, 16 q rows/wave.
// Single-buffer LDS (R10 dbuf regressed 11% — reverted):
//   Kt: [64kv][64dk] XOR-swizzled (byte ^= (row&7)<<4)
//   Vt: [64dk][64 kv-PERMUTED] transposed at staging.
// V-COLUMN PERMUTATION: MFMA contracts over k-slots, so permuting BOTH V's
// and P^T's k-index by the same pi is algebraically invisible. Choosing
// col_new(kv) = (kv&32)|((kv&12)<<1)|((kv&16)>>2)|(kv&3) makes the PV
// B-fragment exactly the lane's own packed pkk registers -> the 16-bpermute
// P-gather of earlier rounds is deleted. col_new preserves bit0, so the
// kv-pair staging trick still writes adjacent columns.
// QK^T swapped (sacc rows=kv, cols=q); softmax log2-domain + T13 defer-max;
// next KV tile reg-prefetched during compute (T14).
// NOTE: no min-waves in launch_bounds (R7: register cap -> 456MB spill).
// ---------------------------------------------------------------------------
__global__ __launch_bounds__(256) void attn_fwd(
    const unsigned short* __restrict__ Qb, const unsigned short* __restrict__ Kb,
    const unsigned short* __restrict__ Vb, unsigned short* __restrict__ Xb) {
    __shared__ alignas(16) unsigned short Kt[64 * 64];
    __shared__ alignas(16) unsigned short Vt[64 * 64];

    constexpr float SCL = 0.18033688f;  // 0.125 * log2(e)

    const int tid = threadIdx.x;
    const int pair = blockIdx.x;  // 0..15
    const int bh = blockIdx.y;
    const int b = bh >> 4, h = bh & 15;
    const int lane = tid & 63, w = tid >> 6;
    const int g = lane >> 4, q15 = lane & 15;

    const unsigned short* Qh = Qb + (size_t)bh * Sn * DKn;
    const unsigned short* Kh = Kb + (size_t)bh * Sn * DKn;
    const unsigned short* Vh = Vb + (size_t)bh * Sn * DKn;

    const int st_row = tid >> 2, st_seg = tid & 3;  // K staging
    const int sv_kv = tid & 63, sv_g = tid >> 6;    // V staging
    const int sel = sv_kv & 1;
    // permuted byte col base in Vt (bit0 of kv preserved by col_new)
    const int kv_even = sv_kv & ~1;
    const unsigned kvp = (unsigned)(((kv_even & 32) | ((kv_even & 12) << 1) |
                                     ((kv_even & 16) >> 2) | (kv_even & 3)) *
                                    2);

    u32x4 kr0, kr1, vr0, vr1;  // prefetch registers
    auto load_kv = [&](int j) {
        kr0 = *(const u32x4*)(Kh + (size_t)(j * 64 + st_row) * DKn + st_seg * 8);
        kr1 = *(const u32x4*)(Kh + (size_t)(j * 64 + st_row) * DKn +
                              (st_seg + 4) * 8);
        vr0 = *(const u32x4*)(Vh + (size_t)(j * 64 + sv_kv) * DKn + sv_g * 8);
        vr1 = *(const u32x4*)(Vh + (size_t)(j * 64 + sv_kv) * DKn + sv_g * 8 + 32);
    };

    for (int hp = 0; hp < 2; ++hp) {
        const int qblk = hp == 0 ? (NQB - 1 - pair) : pair;
        const int qg = qblk * 64 + w * 16 + q15;  // this lane's q row

        short8 qf[2];
#pragma unroll
        for (int ks = 0; ks < 2; ++ks)
            qf[ks] = __builtin_bit_cast(
                short8, *(const u32x4*)(Qh + (size_t)qg * DKn + ks * 32 + g * 8));

        f32x4 xacc[4] = {};  // O^T: xacc[mf][r] = O[q=q15][d=mf*16+4g+r]
        float m_run = -1e30f, l_run = 0.f;

        load_kv(0);
        for (int j = 0; j <= qblk; ++j) {
            // ---- write staged KV regs to LDS ----
            {
                unsigned b0 = ((unsigned)(st_row * 128 + st_seg * 16)) ^
                              ((unsigned)(st_row & 7) << 4);
                unsigned b1 = ((unsigned)(st_row * 128 + (st_seg + 4) * 16)) ^
                              ((unsigned)(st_row & 7) << 4);
                *(u32x4*)((char*)Kt + b0) = kr0;
                *(u32x4*)((char*)Kt + b1) = kr1;
            }
#pragma unroll
            for (int r2 = 0; r2 < 2; ++r2) {
                u32x4 vvec = r2 ? vr1 : vr0;
                int dk0 = sv_g * 8 + r2 * 32;
#pragma unroll
                for (int i = 0; i < 4; ++i) {
                    unsigned mine = vvec[i];
                    unsigned theirs = (unsigned)__shfl_xor((int)mine, 1);
                    int dk_abs = dk0 + 2 * i + sel;
                    unsigned out = sel ? ((theirs >> 16) | (mine & 0xffff0000u))
                                       : ((mine & 0xffffu) | (theirs << 16));
                    unsigned byteoff = ((unsigned)(dk_abs * 128) + kvp) ^
                                       ((unsigned)(dk_abs & 7) << 4);
                    *(unsigned*)((char*)Vt + byteoff) = out;
                }
            }
            __syncthreads();

            // next tile's loads in flight under the compute
            if (j < qblk) load_kv(j + 1);

            // ---- QK^T (swapped): sacc rows = kv, cols = q ----
            f32x4 sacc[4] = {};
#pragma unroll
            for (int mf = 0; mf < 4; ++mf) {
                int row = mf * 16 + q15;
#pragma unroll
                for (int ks = 0; ks < 2; ++ks) {
                    unsigned byteoff = ((unsigned)(row * 128 + ks * 64 + g * 16)) ^
                                       ((unsigned)(row & 7) << 4);
                    short8 kf = __builtin_bit_cast(
                        short8, *(const u32x4*)((char*)Kt + byteoff));
                    sacc[mf] = __builtin_amdgcn_mfma_f32_16x16x32_bf16(
                        kf, qf[ks], sacc[mf], 0, 0, 0);
                }
            }

            // ---- mask + online softmax (log2 domain), lane owns q row qg ----
            float p[4][4];
            float pmax = -1e30f;
            const bool diag = (j == qblk);
#pragma unroll
            for (int mf = 0; mf < 4; ++mf)
#pragma unroll
                for (int r = 0; r < 4; ++r) {
                    float sv = sacc[mf][r] * SCL;
                    if (diag) {
                        int kvg = j * 64 + mf * 16 + 4 * g + r;
                        if (kvg > qg) sv = -1e30f;
                    }
                    p[mf][r] = sv;
                    pmax = fmaxf(pmax, sv);
                }
            pmax = fmaxf(pmax, __shfl_xor(pmax, 16));
            pmax = fmaxf(pmax, __shfl_xor(pmax, 32));
            if (__any(pmax > m_run + 8.f)) {  // T13 defer-max
                float mnew = fmaxf(m_run, pmax);
                float corr = exp2a(m_run - mnew);
                l_run *= corr;
#pragma unroll
                for (int mf = 0; mf < 4; ++mf)
#pragma unroll
                    for (int r = 0; r < 4; ++r) xacc[mf][r] *= corr;
                m_run = mnew;
            }
            float lsum = 0.f;
#pragma unroll
            for (int mf = 0; mf < 4; ++mf)
#pragma unroll
                for (int r = 0; r < 4; ++r) {
                    float e = exp2a(p[mf][r] - m_run);
                    p[mf][r] = e;
                    lsum += e;
                }
            lsum += __shfl_xor(lsum, 16);
            lsum += __shfl_xor(lsum, 32);
            l_run += lsum;

            // ---- pack P; PV B-frag is lane-local (V columns pre-permuted) ----
            unsigned pkk[4][2];
#pragma unroll
            for (int mf = 0; mf < 4; ++mf) {
                pkk[mf][0] = pk2(p[mf][0], p[mf][1]);
                pkk[mf][1] = pk2(p[mf][2], p[mf][3]);
            }
#pragma unroll
            for (int ks = 0; ks < 2; ++ks) {
                u32x4 tmp = {pkk[2 * ks][0], pkk[2 * ks][1], pkk[2 * ks + 1][0],
                             pkk[2 * ks + 1][1]};
                short8 pb = __builtin_bit_cast(short8, tmp);
#pragma unroll
                for (int mf = 0; mf < 4; ++mf) {
                    int row = mf * 16 + q15;
                    unsigned byteoff = ((unsigned)(row * 128 + ks * 64 + g * 16)) ^
                                       ((unsigned)(row & 7) << 4);
                    short8 vf = __builtin_bit_cast(
                        short8, *(const u32x4*)((char*)Vt + byteoff));
                    xacc[mf] = __builtin_amdgcn_mfma_f32_16x16x32_bf16(
                        vf, pb, xacc[mf], 0, 0, 0);
                }
            }
            __syncthreads();
        }

        // ---- epilogue: lane owns q=q15 row; 4x 8B stores ----
        float inv = 1.0f / l_run;
        size_t rowbase = (size_t)(b * Sn + qblk * 64 + w * 16 + q15) * Dn + h * 64;
#pragma unroll
        for (int mf = 0; mf < 4; ++mf) {
            unsigned w0 = pk2(xacc[mf][0] * inv, xacc[mf][1] * inv);
            unsigned w1 = pk2(xacc[mf][2] * inv, xacc[mf][3] * inv);
            uint2 val = {w0, w1};
            *(uint2*)(Xb + rowbase + mf * 16 + 4 * g) = val;
        }
    }
}

// ---------------------------------------------------------------------------
// Launch. ws layout (bf16): Qb | Kb | Vb | Xb (16 MiB each) | Wb (8 MiB,
// 4 weight matrices bf16, if ws_size permits).
// ---------------------------------------------------------------------------
extern "C" void kernel_launch(void* const* d_in, const int* in_sizes, int n_in,
                              void* d_out, int out_size, void* d_ws, size_t ws_size,
                              hipStream_t stream) {
    (void)in_sizes; (void)n_in; (void)out_size;
    const float* q = (const float*)d_in[0];
    const float* k = (const float*)d_in[1];
    const float* v = (const float*)d_in[2];
    // d_in[3] = mask (causal tril; implemented analytically)
    const float* Wq = (const float*)d_in[4];
    const float* Wk = (const float*)d_in[5];
    const float* Wv = (const float*)d_in[6];
    const float* Wo = (const float*)d_in[7];

    unsigned short* Qb = (unsigned short*)d_ws;
    unsigned short* Kb = Qb + (size_t)Mrows * Dn;
    unsigned short* Vb = Kb + (size_t)Mrows * Dn;
    unsigned short* Xb = Vb + (size_t)Mrows * Dn;
    unsigned short* Wb = Xb + (size_t)Mrows * Dn;

    const size_t needW =
        (size_t)4 * Mrows * Dn * 2 + (size_t)4 * Dn * Dn * 2;  // 64 + 8 MiB
    const bool useWb = ws_size >= needW;

    dim3 blk(256);
    dim3 ggrid(Dn / 128, Mrows / 128);

    if (useWb) {
        cvt_w<<<dim3(Dn * Dn / (256 * 8), 4), blk, 0, stream>>>(Wq, Wk, Wv, Wo, Wb);
        gemm_qkv<<<dim3(Dn / 128, Mrows / 128, 3), blk, 0, stream>>>(q, k, v, Wb,
                                                                     Qb, Kb, Vb);
        attn_fwd<<<dim3(NQB / 2, Bn * Hn), blk, 0, stream>>>(Qb, Kb, Vb, Xb);
        gemm_nt<true, true, true><<<ggrid, blk, 0, stream>>>(
            Xb, Wb + (size_t)3 * Dn * Dn, d_out);
    } else {
        gemm_nt<false, false, false><<<ggrid, blk, 0, stream>>>(q, Wq, Qb);
        gemm_nt<false, false, false><<<ggrid, blk, 0, stream>>>(k, Wk, Kb);
        gemm_nt<false, false, false><<<ggrid, blk, 0, stream>>>(v, Wv, Vb);
        attn_fwd<<<dim3(NQB / 2, Bn * Hn), blk, 0, stream>>>(Qb, Kb, Vb, Xb);
        gemm_nt<true, false, true><<<ggrid, blk, 0, stream>>>(Xb, Wo, d_out);
    }
}

// Round 12
// 227.965 us; speedup vs baseline: 2.1598x; 1.1084x over previous
//
#include <hip/hip_runtime.h>
#include <hip/hip_bf16.h>

// Problem constants
constexpr int Bn = 4, Sn = 2048, Dn = 1024, Hn = 16, DKn = 64;
constexpr int Mrows = Bn * Sn;  // 8192
constexpr int NQB = Sn / 64;    // 32 q-chunks of 64 rows

typedef __attribute__((ext_vector_type(8))) short short8;
typedef __attribute__((ext_vector_type(4))) float f32x4;
typedef __attribute__((ext_vector_type(4))) unsigned int u32x4;

#define DEV __device__ __forceinline__

// fp32 -> bf16 RNE, scalar (epilogue scatter only)
DEV unsigned short f2bf(float f) {
    unsigned u = __builtin_bit_cast(unsigned, f);
    u += 0x7FFFu + ((u >> 16) & 1u);
    return (unsigned short)(u >> 16);
}
// fp32 pair -> packed bf16x2 via v_cvt_pk_bf16_f32 (hardware RNE)
DEV unsigned pk2(float a, float b) {
    __hip_bfloat162 h = __float22bfloat162_rn(float2{a, b});
    unsigned u;
    __builtin_memcpy(&u, &h, 4);
    return u;
}
// 2^x via v_exp_f32
DEV float exp2a(float x) {
    float r;
    asm("v_exp_f32 %0, %1" : "=v"(r) : "v"(x));
    return r;
}

// ---------------------------------------------------------------------------
// Weights fp32 -> bf16, one matrix per blockIdx.y. 8 elems/thread.
// ---------------------------------------------------------------------------
__global__ __launch_bounds__(256) void cvt_w(const float* __restrict__ W0,
                                             const float* __restrict__ W1,
                                             const float* __restrict__ W2,
                                             const float* __restrict__ W3,
                                             unsigned short* __restrict__ Out) {
    const float* src = blockIdx.y == 0 ? W0
                     : blockIdx.y == 1 ? W1
                     : blockIdx.y == 2 ? W2 : W3;
    size_t off = ((size_t)blockIdx.x * 256 + threadIdx.x) * 8;
    const float4* s = (const float4*)(src + off);
    float4 a = s[0], b = s[1];
    u32x4 p = {pk2(a.x, a.y), pk2(a.z, a.w), pk2(b.x, b.y), pk2(b.z, b.w)};
    *(u32x4*)(Out + (size_t)blockIdx.y * (Dn * Dn) + off) = p;
}

// ---------------------------------------------------------------------------
// GEMM body: C[m,n] = sum_k A[m,k] * W[n,k]  (y = x @ W^T), M=8192, N=K=1024.
// 128x128 tile, BK=32, 256 threads (4 waves, 2x2 wave grid, 64x64 per wave).
// XCD-AWARE REMAP (R11 lesson): with grid (8,64), the 8 n-sibling blocks
// sharing one A-panel get consecutive bids -> different XCDs -> each XCD
// L2-fills the same 512KB A-panel (8x over-fetch, 398MB measured). Decode
// bid so all n-blocks of a panel share bid%8 (= same XCD); per-XCD A set =
// 8 panels = 4MB = L2 size. Bijective -> correctness-independent.
// Reg-prefetch of next K-step during compute. A/B optionally bf16.
// ---------------------------------------------------------------------------
template <bool ABF16, bool BBF16, bool OUTF32>
DEV void gemm_body(const void* __restrict__ Ap, const void* __restrict__ Bw,
                   void* __restrict__ Out) {
    __shared__ alignas(16) unsigned short As[128 * 40];
    __shared__ alignas(16) unsigned short Bs[128 * 40];

    const int tid = threadIdx.x;
    const int bid = (int)(blockIdx.y * gridDim.x + blockIdx.x);
    const int xcd = bid & 7;
    const int jj = bid >> 3;
    const int m0 = (xcd + ((jj & 7) << 3)) * 128;  // 64 m-panels
    const int n0 = (jj >> 3) * 128;                // 8 n-panels
    const int lane = tid & 63;
    const int w = tid >> 6;
    const int wm = (w >> 1) * 64, wn = (w & 1) * 64;
    const int g = lane >> 4, q15 = lane & 15;

    f32x4 acc[4][4] = {};

    const int srow = tid >> 1, shalf = tid & 1;

    const float* Af = (const float*)Ap;
    const unsigned short* Ab = (const unsigned short*)Ap;
    const float* Bf = (const float*)Bw;
    const unsigned short* Bb = (const unsigned short*)Bw;

    float4 fa0, fa1, fa2, fa3, fb0, fb1, fb2, fb3;
    u32x4 ua0, ua1, ub0, ub1;

    auto loadA = [&](int kk) {
        if constexpr (ABF16) {
            const u32x4* s =
                (const u32x4*)(Ab + (size_t)(m0 + srow) * Dn + kk + shalf * 16);
            ua0 = s[0];
            ua1 = s[1];
        } else {
            const float4* s =
                (const float4*)(Af + (size_t)(m0 + srow) * Dn + kk + shalf * 16);
            fa0 = s[0]; fa1 = s[1]; fa2 = s[2]; fa3 = s[3];
        }
    };
    auto loadB = [&](int kk) {
        if constexpr (BBF16) {
            const u32x4* s =
                (const u32x4*)(Bb + (size_t)(n0 + srow) * Dn + kk + shalf * 16);
            ub0 = s[0];
            ub1 = s[1];
        } else {
            const float4* s =
                (const float4*)(Bf + (size_t)(n0 + srow) * Dn + kk + shalf * 16);
            fb0 = s[0]; fb1 = s[1]; fb2 = s[2]; fb3 = s[3];
        }
    };
    auto store = [&]() {
        u32x4* da = (u32x4*)(&As[srow * 40 + shalf * 16]);
        if constexpr (ABF16) {
            da[0] = ua0;
            da[1] = ua1;
        } else {
            u32x4 p0 = {pk2(fa0.x, fa0.y), pk2(fa0.z, fa0.w), pk2(fa1.x, fa1.y),
                        pk2(fa1.z, fa1.w)};
            u32x4 p1 = {pk2(fa2.x, fa2.y), pk2(fa2.z, fa2.w), pk2(fa3.x, fa3.y),
                        pk2(fa3.z, fa3.w)};
            da[0] = p0;
            da[1] = p1;
        }
        u32x4* db = (u32x4*)(&Bs[srow * 40 + shalf * 16]);
        if constexpr (BBF16) {
            db[0] = ub0;
            db[1] = ub1;
        } else {
            u32x4 q0 = {pk2(fb0.x, fb0.y), pk2(fb0.z, fb0.w), pk2(fb1.x, fb1.y),
                        pk2(fb1.z, fb1.w)};
            u32x4 q1 = {pk2(fb2.x, fb2.y), pk2(fb2.z, fb2.w), pk2(fb3.x, fb3.y),
                        pk2(fb3.z, fb3.w)};
            db[0] = q0;
            db[1] = q1;
        }
    };

    loadA(0);
    loadB(0);
    for (int kk = 0; kk < Dn; kk += 32) {
        store();
        __syncthreads();
        if (kk + 32 < Dn) {
            loadA(kk + 32);
            loadB(kk + 32);
        }

        short8 af[4], bf[4];
#pragma unroll
        for (int mf = 0; mf < 4; ++mf)
            af[mf] = __builtin_bit_cast(
                short8, *(const u32x4*)(&As[(wm + mf * 16 + q15) * 40 + g * 8]));
#pragma unroll
        for (int nf = 0; nf < 4; ++nf)
            bf[nf] = __builtin_bit_cast(
                short8, *(const u32x4*)(&Bs[(wn + nf * 16 + q15) * 40 + g * 8]));
#pragma unroll
        for (int mf = 0; mf < 4; ++mf)
#pragma unroll
            for (int nf = 0; nf < 4; ++nf)
                acc[mf][nf] = __builtin_amdgcn_mfma_f32_16x16x32_bf16(
                    af[mf], bf[nf], acc[mf][nf], 0, 0, 0);
        __syncthreads();
    }

#pragma unroll
    for (int mf = 0; mf < 4; ++mf)
#pragma unroll
        for (int nf = 0; nf < 4; ++nf)
#pragma unroll
            for (int r = 0; r < 4; ++r) {
                int m = m0 + wm + mf * 16 + 4 * g + r;
                int n = n0 + wn + nf * 16 + q15;
                float val = acc[mf][nf][r];
                if (OUTF32) {
                    ((float*)Out)[(size_t)m * Dn + n] = val;
                } else {
                    int b = m >> 11, s = m & (Sn - 1);
                    int h = n >> 6, dk = n & 63;
                    ((unsigned short*)Out)[(((size_t)(b * Hn + h) * Sn + s) << 6) +
                                           dk] = f2bf(val);
                }
            }
}

template <bool ABF16, bool BBF16, bool OUTF32>
__global__ __launch_bounds__(256) void gemm_nt(const void* __restrict__ Ap,
                                               const void* __restrict__ Bw,
                                               void* __restrict__ Out) {
    gemm_body<ABF16, BBF16, OUTF32>(Ap, Bw, Out);
}

// ---------------------------------------------------------------------------
// Causal flash attention, load-balanced pairs: block p runs chunk 31-p then
// chunk p (uniform 33 KV-iterations). 256 threads = 4 waves, 16 q rows/wave.
// Single-buffer LDS:
//   Kt: [64kv][64dk] XOR-swizzled (byte ^= (row&7)<<4)
//   Vt: [64dk][64 kv-PERMUTED] transposed at staging.
// V-COLUMN PERMUTATION (R11 win, 134.8 -> ~65us): MFMA contracts over
// k-slots, so permuting BOTH V's and P^T's k-index by the same pi is
// algebraically invisible. col_new(kv) = (kv&32)|((kv&12)<<1)|((kv&16)>>2)|
// (kv&3) makes the PV B-fragment exactly the lane's own packed pkk regs ->
// no P-gather shuffles. col_new preserves bit0 (kv-pair staging intact).
// QK^T swapped (sacc rows=kv, cols=q); softmax log2-domain + T13 defer-max;
// next KV tile reg-prefetched during compute (T14).
// NOTE: no min-waves in launch_bounds (R7: register cap -> 456MB spill).
// ---------------------------------------------------------------------------
__global__ __launch_bounds__(256) void attn_fwd(
    const unsigned short* __restrict__ Qb, const unsigned short* __restrict__ Kb,
    const unsigned short* __restrict__ Vb, unsigned short* __restrict__ Xb) {
    __shared__ alignas(16) unsigned short Kt[64 * 64];
    __shared__ alignas(16) unsigned short Vt[64 * 64];

    constexpr float SCL = 0.18033688f;  // 0.125 * log2(e)

    const int tid = threadIdx.x;
    const int pair = blockIdx.x;  // 0..15
    const int bh = blockIdx.y;
    const int b = bh >> 4, h = bh & 15;
    const int lane = tid & 63, w = tid >> 6;
    const int g = lane >> 4, q15 = lane & 15;

    const unsigned short* Qh = Qb + (size_t)bh * Sn * DKn;
    const unsigned short* Kh = Kb + (size_t)bh * Sn * DKn;
    const unsigned short* Vh = Vb + (size_t)bh * Sn * DKn;

    const int st_row = tid >> 2, st_seg = tid & 3;  // K staging
    const int sv_kv = tid & 63, sv_g = tid >> 6;    // V staging
    const int sel = sv_kv & 1;
    // permuted byte col base in Vt (bit0 of kv preserved by col_new)
    const int kv_even = sv_kv & ~1;
    const unsigned kvp = (unsigned)(((kv_even & 32) | ((kv_even & 12) << 1) |
                                     ((kv_even & 16) >> 2) | (kv_even & 3)) *
                                    2);

    u32x4 kr0, kr1, vr0, vr1;  // prefetch registers
    auto load_kv = [&](int j) {
        kr0 = *(const u32x4*)(Kh + (size_t)(j * 64 + st_row) * DKn + st_seg * 8);
        kr1 = *(const u32x4*)(Kh + (size_t)(j * 64 + st_row) * DKn +
                              (st_seg + 4) * 8);
        vr0 = *(const u32x4*)(Vh + (size_t)(j * 64 + sv_kv) * DKn + sv_g * 8);
        vr1 = *(const u32x4*)(Vh + (size_t)(j * 64 + sv_kv) * DKn + sv_g * 8 + 32);
    };

    for (int hp = 0; hp < 2; ++hp) {
        const int qblk = hp == 0 ? (NQB - 1 - pair) : pair;
        const int qg = qblk * 64 + w * 16 + q15;  // this lane's q row

        short8 qf[2];
#pragma unroll
        for (int ks = 0; ks < 2; ++ks)
            qf[ks] = __builtin_bit_cast(
                short8, *(const u32x4*)(Qh + (size_t)qg * DKn + ks * 32 + g * 8));

        f32x4 xacc[4] = {};  // O^T: xacc[mf][r] = O[q=q15][d=mf*16+4g+r]
        float m_run = -1e30f, l_run = 0.f;

        load_kv(0);
        for (int j = 0; j <= qblk; ++j) {
            // ---- write staged KV regs to LDS ----
            {
                unsigned b0 = ((unsigned)(st_row * 128 + st_seg * 16)) ^
                              ((unsigned)(st_row & 7) << 4);
                unsigned b1 = ((unsigned)(st_row * 128 + (st_seg + 4) * 16)) ^
                              ((unsigned)(st_row & 7) << 4);
                *(u32x4*)((char*)Kt + b0) = kr0;
                *(u32x4*)((char*)Kt + b1) = kr1;
            }
#pragma unroll
            for (int r2 = 0; r2 < 2; ++r2) {
                u32x4 vvec = r2 ? vr1 : vr0;
                int dk0 = sv_g * 8 + r2 * 32;
#pragma unroll
                for (int i = 0; i < 4; ++i) {
                    unsigned mine = vvec[i];
                    unsigned theirs = (unsigned)__shfl_xor((int)mine, 1);
                    int dk_abs = dk0 + 2 * i + sel;
                    unsigned out = sel ? ((theirs >> 16) | (mine & 0xffff0000u))
                                       : ((mine & 0xffffu) | (theirs << 16));
                    unsigned byteoff = ((unsigned)(dk_abs * 128) + kvp) ^
                                       ((unsigned)(dk_abs & 7) << 4);
                    *(unsigned*)((char*)Vt + byteoff) = out;
                }
            }
            __syncthreads();

            // next tile's loads in flight under the compute
            if (j < qblk) load_kv(j + 1);

            // ---- QK^T (swapped): sacc rows = kv, cols = q ----
            f32x4 sacc[4] = {};
#pragma unroll
            for (int mf = 0; mf < 4; ++mf) {
                int row = mf * 16 + q15;
#pragma unroll
                for (int ks = 0; ks < 2; ++ks) {
                    unsigned byteoff = ((unsigned)(row * 128 + ks * 64 + g * 16)) ^
                                       ((unsigned)(row & 7) << 4);
                    short8 kf = __builtin_bit_cast(
                        short8, *(const u32x4*)((char*)Kt + byteoff));
                    sacc[mf] = __builtin_amdgcn_mfma_f32_16x16x32_bf16(
                        kf, qf[ks], sacc[mf], 0, 0, 0);
                }
            }

            // ---- mask + online softmax (log2 domain), lane owns q row qg ----
            float p[4][4];
            float pmax = -1e30f;
            const bool diag = (j == qblk);
#pragma unroll
            for (int mf = 0; mf < 4; ++mf)
#pragma unroll
                for (int r = 0; r < 4; ++r) {
                    float sv = sacc[mf][r] * SCL;
                    if (diag) {
                        int kvg = j * 64 + mf * 16 + 4 * g + r;
                        if (kvg > qg) sv = -1e30f;
                    }
                    p[mf][r] = sv;
                    pmax = fmaxf(pmax, sv);
                }
            pmax = fmaxf(pmax, __shfl_xor(pmax, 16));
            pmax = fmaxf(pmax, __shfl_xor(pmax, 32));
            if (__any(pmax > m_run + 8.f)) {  // T13 defer-max
                float mnew = fmaxf(m_run, pmax);
                float corr = exp2a(m_run - mnew);
                l_run *= corr;
#pragma unroll
                for (int mf = 0; mf < 4; ++mf)
#pragma unroll
                    for (int r = 0; r < 4; ++r) xacc[mf][r] *= corr;
                m_run = mnew;
            }
            float lsum = 0.f;
#pragma unroll
            for (int mf = 0; mf < 4; ++mf)
#pragma unroll
                for (int r = 0; r < 4; ++r) {
                    float e = exp2a(p[mf][r] - m_run);
                    p[mf][r] = e;
                    lsum += e;
                }
            lsum += __shfl_xor(lsum, 16);
            lsum += __shfl_xor(lsum, 32);
            l_run += lsum;

            // ---- pack P; PV B-frag is lane-local (V columns pre-permuted) ----
            unsigned pkk[4][2];
#pragma unroll
            for (int mf = 0; mf < 4; ++mf) {
                pkk[mf][0] = pk2(p[mf][0], p[mf][1]);
                pkk[mf][1] = pk2(p[mf][2], p[mf][3]);
            }
#pragma unroll
            for (int ks = 0; ks < 2; ++ks) {
                u32x4 tmp = {pkk[2 * ks][0], pkk[2 * ks][1], pkk[2 * ks + 1][0],
                             pkk[2 * ks + 1][1]};
                short8 pb = __builtin_bit_cast(short8, tmp);
#pragma unroll
                for (int mf = 0; mf < 4; ++mf) {
                    int row = mf * 16 + q15;
                    unsigned byteoff = ((unsigned)(row * 128 + ks * 64 + g * 16)) ^
                                       ((unsigned)(row & 7) << 4);
                    short8 vf = __builtin_bit_cast(
                        short8, *(const u32x4*)((char*)Vt + byteoff));
                    xacc[mf] = __builtin_amdgcn_mfma_f32_16x16x32_bf16(
                        vf, pb, xacc[mf], 0, 0, 0);
                }
            }
            __syncthreads();
        }

        // ---- epilogue: lane owns q=q15 row; 4x 8B stores ----
        float inv = 1.0f / l_run;
        size_t rowbase = (size_t)(b * Sn + qblk * 64 + w * 16 + q15) * Dn + h * 64;
#pragma unroll
        for (int mf = 0; mf < 4; ++mf) {
            unsigned w0 = pk2(xacc[mf][0] * inv, xacc[mf][1] * inv);
            unsigned w1 = pk2(xacc[mf][2] * inv, xacc[mf][3] * inv);
            uint2 val = {w0, w1};
            *(uint2*)(Xb + rowbase + mf * 16 + 4 * g) = val;
        }
    }
}

// ---------------------------------------------------------------------------
// Launch. ws layout (bf16): Qb | Kb | Vb | Xb (16 MiB each) | Wb (8 MiB,
// 4 weight matrices bf16, if ws_size permits). QKV fusion reverted (R11:
// fused dispatch thrashed L2, 147us vs ~100us separate).
// ---------------------------------------------------------------------------
extern "C" void kernel_launch(void* const* d_in, const int* in_sizes, int n_in,
                              void* d_out, int out_size, void* d_ws, size_t ws_size,
                              hipStream_t stream) {
    (void)in_sizes; (void)n_in; (void)out_size;
    const float* q = (const float*)d_in[0];
    const float* k = (const float*)d_in[1];
    const float* v = (const float*)d_in[2];
    // d_in[3] = mask (causal tril; implemented analytically)
    const float* Wq = (const float*)d_in[4];
    const float* Wk = (const float*)d_in[5];
    const float* Wv = (const float*)d_in[6];
    const float* Wo = (const float*)d_in[7];

    unsigned short* Qb = (unsigned short*)d_ws;
    unsigned short* Kb = Qb + (size_t)Mrows * Dn;
    unsigned short* Vb = Kb + (size_t)Mrows * Dn;
    unsigned short* Xb = Vb + (size_t)Mrows * Dn;
    unsigned short* Wb = Xb + (size_t)Mrows * Dn;

    const size_t needW =
        (size_t)4 * Mrows * Dn * 2 + (size_t)4 * Dn * Dn * 2;  // 64 + 8 MiB
    const bool useWb = ws_size >= needW;

    dim3 blk(256);
    dim3 ggrid(Dn / 128, Mrows / 128);

    if (useWb) {
        cvt_w<<<dim3(Dn * Dn / (256 * 8), 4), blk, 0, stream>>>(Wq, Wk, Wv, Wo, Wb);
        const unsigned short* Wqb = Wb;
        const unsigned short* Wkb = Wb + (size_t)Dn * Dn;
        const unsigned short* Wvb = Wb + (size_t)2 * Dn * Dn;
        const unsigned short* Wob = Wb + (size_t)3 * Dn * Dn;
        gemm_nt<false, true, false><<<ggrid, blk, 0, stream>>>(q, Wqb, Qb);
        gemm_nt<false, true, false><<<ggrid, blk, 0, stream>>>(k, Wkb, Kb);
        gemm_nt<false, true, false><<<ggrid, blk, 0, stream>>>(v, Wvb, Vb);
        attn_fwd<<<dim3(NQB / 2, Bn * Hn), blk, 0, stream>>>(Qb, Kb, Vb, Xb);
        gemm_nt<true, true, true><<<ggrid, blk, 0, stream>>>(Xb, Wob, d_out);
    } else {
        gemm_nt<false, false, false><<<ggrid, blk, 0, stream>>>(q, Wq, Qb);
        gemm_nt<false, false, false><<<ggrid, blk, 0, stream>>>(k, Wk, Kb);
        gemm_nt<false, false, false><<<ggrid, blk, 0, stream>>>(v, Wv, Vb);
        attn_fwd<<<dim3(NQB / 2, Bn * Hn), blk, 0, stream>>>(Qb, Kb, Vb, Xb);
        gemm_nt<true, false, true><<<ggrid, blk, 0, stream>>>(Xb, Wo, d_out);
    }
}